// Round 1
// baseline (2790.925 us; speedup 1.0000x reference)
//
#include <hip/hip_runtime.h>

// ---------------- problem constants ----------------
constexpr int CB   = 8;      // batch
constexpr int CN   = 1369;   // tokens (37*37)
constexpr int CDIN = 768;
constexpr int CS   = 7;      // slots
constexpr int CD   = 256;
constexpr int CITERS = 3;
constexpr int CRES = 37;
constexpr float CSIGMA = 5.0f;
constexpr int CBS = CB * CS;        // 56
constexpr int CRT = CBS * CN;       // 76664 rows for f_mlp
constexpr int CBN = CB * CN;        // 10952 rows for initial mlp
constexpr float LNEPS = 1e-5f;
constexpr float ATTN_EPS = 1e-8f;

// ---------------- helpers ----------------
__device__ __forceinline__ float ag_x(int n) { return -1.f + (float)(n % CRES) * (2.f / 36.f); }
__device__ __forceinline__ float ag_y(int n) { return -1.f + (float)(n / CRES) * (2.f / 36.f); }

// 256-thread block sum
__device__ __forceinline__ float block_reduce_sum(float v, float* sbuf) {
    #pragma unroll
    for (int off = 32; off > 0; off >>= 1) v += __shfl_down(v, off, 64);
    if ((threadIdx.x & 63) == 0) sbuf[threadIdx.x >> 6] = v;
    __syncthreads();
    if (threadIdx.x == 0) sbuf[0] = sbuf[0] + sbuf[1] + sbuf[2] + sbuf[3];
    __syncthreads();
    float r = sbuf[0];
    __syncthreads();
    return r;
}

// ---------------- layernorm over rows ----------------
__global__ __launch_bounds__(256) void ln_kernel(const float* __restrict__ in,
                                                 float* __restrict__ out,
                                                 const float* __restrict__ g,
                                                 const float* __restrict__ b, int d) {
    __shared__ float sbuf[8];
    int row = blockIdx.x;
    const float* x = in + (size_t)row * d;
    float* y = out + (size_t)row * d;
    float s = 0.f;
    for (int i = threadIdx.x; i < d; i += 256) s += x[i];
    float mean = block_reduce_sum(s, sbuf) / d;
    float v = 0.f;
    for (int i = threadIdx.x; i < d; i += 256) { float t = x[i] - mean; v += t * t; }
    float var = block_reduce_sum(v, sbuf) / d;
    float rstd = rsqrtf(var + LNEPS);
    for (int i = threadIdx.x; i < d; i += 256) y[i] = (x[i] - mean) * rstd * g[i] + b[i];
}

// ---------------- tiled SGEMM 128x128x8, 256 threads, 8x8 micro ----------------
// MODE 0: C = act(A@B + bias)
// MODE 1: A[r,c] = base[(b,n),c] + rel0*gw[0,c] + rel1*gw[1,c] + gb[c]; store relu(...)
// MODE 2: epilogue: dots[r] += scale * sum_c (A@B + bias)[r,c] * q[bs(r),c]   (atomic)
// MODE 3: epilogue: upd[bs(r),c] += attn[r] * (A@B + bias)[r,c]               (atomic)
template<int MODE>
__global__ __launch_bounds__(256)
void gemm_k(const float* __restrict__ A, const float* __restrict__ Bw,
            float* __restrict__ C, const float* __restrict__ bias,
            int M, int Nc, int K, int do_relu,
            const float* __restrict__ base, const float* __restrict__ relv,
            const float* __restrict__ gw, const float* __restrict__ gb,
            const float* __restrict__ qv, float* __restrict__ dots,
            const float* __restrict__ attn, float* __restrict__ upd) {
    __shared__ float smem[2048];          // As[8][128] | Bs[8][128]; reused as red[128][16]
    float* As = smem;
    float* Bs = smem + 1024;
    const int tid = threadIdx.x;
    const int tm = tid >> 4, tn = tid & 15;
    const int m0 = blockIdx.x * 128, n0 = blockIdx.y * 128;

    const int arow = tid >> 1;
    const int acol4 = (tid & 1) * 4;
    const int grow = m0 + arow;
    const int growc = (grow < M) ? grow : (M - 1);
    const int brow = tid >> 5;
    const int bcol4 = (tid & 31) * 4;

    int baserow = 0; float rel0 = 0.f, rel1 = 0.f;
    if constexpr (MODE == 1) {
        int bidx = growc / (CS * CN);
        int rem = growc - bidx * (CS * CN);
        int sidx = rem / CN;
        int nidx = rem - sidx * CN;
        baserow = bidx * CN + nidx;
        rel0 = relv[2 * growc];
        rel1 = relv[2 * growc + 1];
    }

    float acc[8][8];
    #pragma unroll
    for (int i = 0; i < 8; i++)
        #pragma unroll
        for (int j = 0; j < 8; j++) acc[i][j] = 0.f;

    for (int k0 = 0; k0 < K; k0 += 8) {
        float4 av, bv;
        if constexpr (MODE == 1) {
            int c = k0 + acol4;
            const float4 b4  = *(const float4*)(base + (size_t)baserow * CD + c);
            const float4 g0  = *(const float4*)(gw + c);
            const float4 g1  = *(const float4*)(gw + CD + c);
            const float4 gb4 = *(const float4*)(gb + c);
            av.x = b4.x + rel0 * g0.x + rel1 * g1.x + gb4.x;
            av.y = b4.y + rel0 * g0.y + rel1 * g1.y + gb4.y;
            av.z = b4.z + rel0 * g0.z + rel1 * g1.z + gb4.z;
            av.w = b4.w + rel0 * g0.w + rel1 * g1.w + gb4.w;
        } else {
            av = *(const float4*)(A + (size_t)growc * K + k0 + acol4);
        }
        bv = *(const float4*)(Bw + (size_t)(k0 + brow) * Nc + n0 + bcol4);
        __syncthreads();
        As[(acol4 + 0) * 128 + arow] = av.x;
        As[(acol4 + 1) * 128 + arow] = av.y;
        As[(acol4 + 2) * 128 + arow] = av.z;
        As[(acol4 + 3) * 128 + arow] = av.w;
        *(float4*)(Bs + brow * 128 + bcol4) = bv;
        __syncthreads();
        #pragma unroll
        for (int kk = 0; kk < 8; kk++) {
            float4 a0 = *(const float4*)(As + kk * 128 + tm * 8);
            float4 a1 = *(const float4*)(As + kk * 128 + tm * 8 + 4);
            float4 b0 = *(const float4*)(Bs + kk * 128 + tn * 8);
            float4 b1 = *(const float4*)(Bs + kk * 128 + tn * 8 + 4);
            float aa[8] = {a0.x, a0.y, a0.z, a0.w, a1.x, a1.y, a1.z, a1.w};
            float bb[8] = {b0.x, b0.y, b0.z, b0.w, b1.x, b1.y, b1.z, b1.w};
            #pragma unroll
            for (int i = 0; i < 8; i++)
                #pragma unroll
                for (int j = 0; j < 8; j++)
                    acc[i][j] += aa[i] * bb[j];
        }
    }
    __syncthreads();   // allow smem reuse in epilogues

    float fb[8];
    #pragma unroll
    for (int j = 0; j < 8; j++) fb[j] = bias ? bias[n0 + tn * 8 + j] : 0.f;

    if constexpr (MODE == 0 || MODE == 1) {
        #pragma unroll
        for (int i = 0; i < 8; i++) {
            int gm = m0 + tm * 8 + i;
            if (gm < M) {
                float o[8];
                #pragma unroll
                for (int j = 0; j < 8; j++) {
                    float v = acc[i][j] + fb[j];
                    if (do_relu) v = fmaxf(v, 0.f);
                    o[j] = v;
                }
                float* crow = C + (size_t)gm * Nc + n0 + tn * 8;
                *(float4*)(crow)     = make_float4(o[0], o[1], o[2], o[3]);
                *(float4*)(crow + 4) = make_float4(o[4], o[5], o[6], o[7]);
            }
        }
    } else if constexpr (MODE == 2) {
        #pragma unroll
        for (int i = 0; i < 8; i++) {
            int gm = m0 + tm * 8 + i;
            float p = 0.f;
            if (gm < M) {
                int bs = gm / CN;
                const float* qr = qv + bs * CD + n0 + tn * 8;
                #pragma unroll
                for (int j = 0; j < 8; j++) p += (acc[i][j] + fb[j]) * qr[j];
            }
            smem[(tm * 8 + i) * 16 + tn] = p;
        }
        __syncthreads();
        if (tid < 128) {
            int gm = m0 + tid;
            if (gm < M) {
                float s = 0.f;
                #pragma unroll
                for (int w = 0; w < 16; w++) s += smem[tid * 16 + w];
                atomicAdd(&dots[gm], s * 0.0625f);   // scale = D^-0.5 = 1/16
            }
        }
    } else {  // MODE 3 — a 128-row tile spans at most 2 (b,s) groups since N=1369>128
        int bs0 = m0 / CN;
        float av8[8]; int grp[8];
        #pragma unroll
        for (int i = 0; i < 8; i++) {
            int gm = m0 + tm * 8 + i;
            if (gm < M) { grp[i] = gm / CN - bs0; av8[i] = attn[gm]; }
            else        { grp[i] = -1; av8[i] = 0.f; }
        }
        for (int g = 0; g < 2; g++) {
            #pragma unroll
            for (int j = 0; j < 8; j++) {
                float s = 0.f;
                #pragma unroll
                for (int i = 0; i < 8; i++)
                    if (grp[i] == g) s += (acc[i][j] + fb[j]) * av8[i];
                smem[(tn * 8 + j) * 16 + tm] = s;
            }
            __syncthreads();
            if (tid < 128) {
                int bsg = bs0 + g;
                if (bsg < CBS) {
                    float s = 0.f;
                    #pragma unroll
                    for (int w = 0; w < 16; w++) s += smem[tid * 16 + w];
                    atomicAdd(&upd[bsg * CD + n0 + tid], s);
                }
            }
            __syncthreads();
        }
    }
}

// ---------------- small kernels ----------------
__global__ __launch_bounds__(256) void init_kernel(const float* __restrict__ slots_init_p,
        const float* __restrict__ S_s0, const float* __restrict__ S_p0,
        float* __restrict__ slots, float* __restrict__ S_s, float* __restrict__ S_p) {
    int bs = blockIdx.x, t = threadIdx.x;
    int s = bs % CS;
    slots[bs * CD + t] = slots_init_p[s * CD + t];
    if (t < 2) { S_s[bs * 2 + t] = S_s0[s * 2 + t]; S_p[bs * 2 + t] = S_p0[s * 2 + t]; }
}

__global__ __launch_bounds__(256) void slots_q_kernel(const float* __restrict__ slots,
        const float* __restrict__ ln_g, const float* __restrict__ ln_b,
        const float* __restrict__ Wq, float* __restrict__ q) {
    __shared__ float sn[CD];
    __shared__ float sbuf[8];
    int row = blockIdx.x, t = threadIdx.x;
    float x = slots[row * CD + t];
    float mean = block_reduce_sum(x, sbuf) / CD;
    float d0 = x - mean;
    float var = block_reduce_sum(d0 * d0, sbuf) / CD;
    sn[t] = d0 * rsqrtf(var + LNEPS) * ln_g[t] + ln_b[t];
    __syncthreads();
    float acc = 0.f;
    for (int j = 0; j < CD; j++) acc += sn[j] * Wq[j * CD + t];
    q[row * CD + t] = acc;
}

__global__ __launch_bounds__(256) void rel_kernel(const float* __restrict__ S_p,
        const float* __restrict__ S_s, float* __restrict__ relv) {
    int r = blockIdx.x * 256 + threadIdx.x;
    if (r >= CRT) return;
    int bs = r / CN;
    int n = r - bs * CN;
    relv[2 * r]     = (ag_x(n) - S_p[2 * bs])     / (S_s[2 * bs]     * CSIGMA);
    relv[2 * r + 1] = (ag_y(n) - S_p[2 * bs + 1]) / (S_s[2 * bs + 1] * CSIGMA);
}

__global__ __launch_bounds__(256) void softmax_kernel(float* __restrict__ dots) {
    int idx = blockIdx.x * 256 + threadIdx.x;
    if (idx >= CBN) return;
    int b = idx / CN, n = idx - b * CN;
    float v[CS]; float mx = -1e30f;
    #pragma unroll
    for (int s = 0; s < CS; s++) { v[s] = dots[(size_t)(b * CS + s) * CN + n]; mx = fmaxf(mx, v[s]); }
    float sum = 0.f;
    #pragma unroll
    for (int s = 0; s < CS; s++) { v[s] = __expf(v[s] - mx); sum += v[s]; }
    float inv = 1.f / sum;
    #pragma unroll
    for (int s = 0; s < CS; s++) dots[(size_t)(b * CS + s) * CN + n] = v[s] * inv + ATTN_EPS;
}

__global__ __launch_bounds__(256) void attn_moments_kernel(const float* __restrict__ u,
        float* __restrict__ attn_out, float* __restrict__ S_p, float* __restrict__ S_s) {
    __shared__ float sbuf[8];
    int bs = blockIdx.x;
    const float* up = u + (size_t)bs * CN;
    float m0 = 0, m1x = 0, m1y = 0, m2x = 0, m2y = 0;
    for (int n = threadIdx.x; n < CN; n += 256) {
        float uu = up[n];
        float ax = ag_x(n), ay = ag_y(n);
        m0 += uu; m1x += uu * ax; m1y += uu * ay; m2x += uu * ax * ax; m2y += uu * ay * ay;
    }
    m0  = block_reduce_sum(m0, sbuf);
    m1x = block_reduce_sum(m1x, sbuf);
    m1y = block_reduce_sum(m1y, sbuf);
    m2x = block_reduce_sum(m2x, sbuf);
    m2y = block_reduce_sum(m2y, sbuf);
    float px = m1x / m0, py = m1y / m0;
    if (threadIdx.x == 0) {
        S_p[2 * bs] = px; S_p[2 * bs + 1] = py;
        S_s[2 * bs]     = sqrtf(fmaxf(m2x / m0 - px * px, 0.f));
        S_s[2 * bs + 1] = sqrtf(fmaxf(m2y / m0 - py * py, 0.f));
    }
    float inv = 1.f / m0;
    for (int n = threadIdx.x; n < CN; n += 256) attn_out[(size_t)bs * CN + n] = up[n] * inv;
}

__global__ __launch_bounds__(256) void gru_mlp_kernel(const float* __restrict__ upd,
        float* __restrict__ slots,
        const float* __restrict__ wih, const float* __restrict__ whh,
        const float* __restrict__ bih, const float* __restrict__ bhh,
        const float* __restrict__ mg, const float* __restrict__ mb,
        const float* __restrict__ w1, const float* __restrict__ b1,
        const float* __restrict__ w2, const float* __restrict__ b2) {
    __shared__ float sU[CD], sH[CD], sM[CD], sH1[4 * CD];
    __shared__ float sbuf[8];
    int row = blockIdx.x, t = threadIdx.x;
    sU[t] = upd[row * CD + t];
    sH[t] = slots[row * CD + t];
    __syncthreads();
    float gi0 = bih[t], gi1 = bih[CD + t], gi2 = bih[2 * CD + t];
    float gh0 = bhh[t], gh1 = bhh[CD + t], gh2 = bhh[2 * CD + t];
    for (int j = 0; j < CD; j++) {
        float uj = sU[j], hj = sH[j];
        gi0 += uj * wih[j * 3 * CD + t];
        gi1 += uj * wih[j * 3 * CD + CD + t];
        gi2 += uj * wih[j * 3 * CD + 2 * CD + t];
        gh0 += hj * whh[j * 3 * CD + t];
        gh1 += hj * whh[j * 3 * CD + CD + t];
        gh2 += hj * whh[j * 3 * CD + 2 * CD + t];
    }
    float r = 1.f / (1.f + expf(-(gi0 + gh0)));
    float z = 1.f / (1.f + expf(-(gi1 + gh1)));
    float nn = tanhf(gi2 + r * gh2);
    float hprev = sH[t];
    float snew = (1.f - z) * nn + z * hprev;
    // pre-norm MLP residual
    float mean = block_reduce_sum(snew, sbuf) / CD;
    float dv = snew - mean;
    float var = block_reduce_sum(dv * dv, sbuf) / CD;
    sM[t] = dv * rsqrtf(var + LNEPS) * mg[t] + mb[t];
    __syncthreads();
    #pragma unroll
    for (int o = 0; o < 4; o++) {
        int c = t + o * 256;
        float a = b1[c];
        for (int j = 0; j < CD; j++) a += sM[j] * w1[j * 4 * CD + c];
        sH1[c] = fmaxf(a, 0.f);
    }
    __syncthreads();
    float out = b2[t];
    for (int j = 0; j < 4 * CD; j++) out += sH1[j] * w2[j * CD + t];
    slots[row * CD + t] = snew + out;
}

__global__ __launch_bounds__(256) void final_kernel(const float* __restrict__ slots,
        const float* __restrict__ fw, const float* __restrict__ fb, float* __restrict__ out) {
    __shared__ float sS[CD];
    int row = blockIdx.x, t = threadIdx.x;
    sS[t] = slots[row * CD + t];
    __syncthreads();
    float a = fb[t];
    for (int j = 0; j < CD; j++) a += sS[j] * fw[j * CD + t];
    out[row * CD + t] = a;
}

// ---------------- launcher ----------------
extern "C" void kernel_launch(void* const* d_in, const int* in_sizes, int n_in,
                              void* d_out, int out_size, void* d_ws, size_t ws_size,
                              hipStream_t stream) {
    (void)in_sizes; (void)n_in; (void)out_size;
    const float* inputs       = (const float*)d_in[0];
    const float* slots_init_p = (const float*)d_in[1];
    const float* S_s0         = (const float*)d_in[2];
    const float* S_p0         = (const float*)d_in[3];
    const float* im_ln1_g = (const float*)d_in[4];
    const float* im_ln1_b = (const float*)d_in[5];
    const float* im_w1    = (const float*)d_in[6];
    const float* im_b1    = (const float*)d_in[7];
    const float* im_w2    = (const float*)d_in[8];
    const float* im_b2    = (const float*)d_in[9];
    const float* im_ln2_g = (const float*)d_in[10];
    const float* im_ln2_b = (const float*)d_in[11];
    const float* Wq  = (const float*)d_in[12];
    const float* Wk  = (const float*)d_in[13];
    const float* Wv  = (const float*)d_in[14];
    const float* g_w = (const float*)d_in[15];
    const float* g_b = (const float*)d_in[16];
    const float* f_w1 = (const float*)d_in[17];
    const float* f_b1 = (const float*)d_in[18];
    const float* f_w2 = (const float*)d_in[19];
    const float* f_b2 = (const float*)d_in[20];
    const float* ln_g = (const float*)d_in[21];
    const float* ln_b = (const float*)d_in[22];
    const float* gru_wih = (const float*)d_in[23];
    const float* gru_whh = (const float*)d_in[24];
    const float* gru_bih = (const float*)d_in[25];
    const float* gru_bhh = (const float*)d_in[26];
    const float* mlp_ln_g = (const float*)d_in[27];
    const float* mlp_ln_b = (const float*)d_in[28];
    const float* mlp_w1 = (const float*)d_in[29];
    const float* mlp_b1 = (const float*)d_in[30];
    const float* mlp_w2 = (const float*)d_in[31];
    const float* mlp_b2 = (const float*)d_in[32];
    const float* fin_w = (const float*)d_in[33];
    const float* fin_b = (const float*)d_in[34];

    float* ws = (float*)d_ws;
    const size_t RA = (size_t)CRT * CD;             // H region, also holds xln|X1 during init
    float* xln = ws;
    float* X1  = ws + (size_t)CBN * CDIN;
    float* H   = ws;
    float* xD  = ws + RA;
    float* KX  = xD + (size_t)CBN * CD;
    float* VX  = KX + (size_t)CBN * CD;
    float* relv = VX + (size_t)CBN * CD;            // [CRT,2]
    float* dots = relv + (size_t)CRT * 2;           // [CRT], also softmax buffer
    float* qb   = dots + CRT;                       // [CBS,CD]
    float* S_pb = qb + CBS * CD;                    // [CBS,2]
    float* S_sb = S_pb + 2 * CBS;
    float* slots = S_sb + 2 * CBS;                  // [CBS,CD]
    float* upd   = slots + CBS * CD;                // [CBS,CD]
    size_t need = (size_t)(upd + CBS * CD - ws) * sizeof(float);
    if (ws_size < need) return;   // insufficient workspace (same behavior every call)

    float* out0 = (float*)d_out;            // [CBS,CD]
    float* attn_out = out0 + CBS * CD;      // [CBS,CN]

    dim3 blk(256);
    const int gM_bn = (CBN + 127) / 128;    // 86
    const int gM_rt = (CRT + 127) / 128;    // 599

    // ---- initial mlp: LN -> Linear+ReLU -> Linear -> LN; then KX/VX projections ----
    ln_kernel<<<CBN, blk, 0, stream>>>(inputs, xln, im_ln1_g, im_ln1_b, CDIN);
    gemm_k<0><<<dim3(gM_bn, 6), blk, 0, stream>>>(xln, im_w1, X1, im_b1, CBN, CDIN, CDIN, 1,
        nullptr, nullptr, nullptr, nullptr, nullptr, nullptr, nullptr, nullptr);
    gemm_k<0><<<dim3(gM_bn, 2), blk, 0, stream>>>(X1, im_w2, xD, im_b2, CBN, CD, CDIN, 0,
        nullptr, nullptr, nullptr, nullptr, nullptr, nullptr, nullptr, nullptr);
    ln_kernel<<<CBN, blk, 0, stream>>>(xD, xD, im_ln2_g, im_ln2_b, CD);
    gemm_k<0><<<dim3(gM_bn, 2), blk, 0, stream>>>(xD, Wk, KX, nullptr, CBN, CD, CD, 0,
        nullptr, nullptr, nullptr, nullptr, nullptr, nullptr, nullptr, nullptr);
    gemm_k<0><<<dim3(gM_bn, 2), blk, 0, stream>>>(xD, Wv, VX, nullptr, CBN, CD, CD, 0,
        nullptr, nullptr, nullptr, nullptr, nullptr, nullptr, nullptr, nullptr);
    init_kernel<<<CBS, blk, 0, stream>>>(slots_init_p, S_s0, S_p0, slots, S_sb, S_pb);

    for (int t = 0; t <= CITERS; t++) {
        slots_q_kernel<<<CBS, blk, 0, stream>>>(slots, ln_g, ln_b, Wq, qb);
        rel_kernel<<<(CRT + 255) / 256, blk, 0, stream>>>(S_pb, S_sb, relv);
        // k path: H = relu((KX + rel@g_w + g_b) @ f_w1 + f_b1)
        gemm_k<1><<<dim3(gM_rt, 2), blk, 0, stream>>>(nullptr, f_w1, H, f_b1, CRT, CD, CD, 1,
            KX, relv, g_w, g_b, nullptr, nullptr, nullptr, nullptr);
        hipMemsetAsync(dots, 0, (size_t)CRT * sizeof(float), stream);
        // dots = (H @ f_w2 + f_b2) . q * scale
        gemm_k<2><<<dim3(gM_rt, 2), blk, 0, stream>>>(H, f_w2, nullptr, f_b2, CRT, CD, CD, 0,
            nullptr, nullptr, nullptr, nullptr, qb, dots, nullptr, nullptr);
        softmax_kernel<<<(CBN + 255) / 256, blk, 0, stream>>>(dots);
        attn_moments_kernel<<<CBS, blk, 0, stream>>>(dots, attn_out, S_pb, S_sb);
        if (t < CITERS) {
            // v path: H = relu((VX + rel@g_w + g_b) @ f_w1 + f_b1)
            gemm_k<1><<<dim3(gM_rt, 2), blk, 0, stream>>>(nullptr, f_w1, H, f_b1, CRT, CD, CD, 1,
                VX, relv, g_w, g_b, nullptr, nullptr, nullptr, nullptr);
            hipMemsetAsync(upd, 0, (size_t)CBS * CD * sizeof(float), stream);
            gemm_k<3><<<dim3(gM_rt, 2), blk, 0, stream>>>(H, f_w2, nullptr, f_b2, CRT, CD, CD, 0,
                nullptr, nullptr, nullptr, nullptr, nullptr, nullptr, attn_out, upd);
            gru_mlp_kernel<<<CBS, blk, 0, stream>>>(upd, slots, gru_wih, gru_whh, gru_bih, gru_bhh,
                mlp_ln_g, mlp_ln_b, mlp_w1, mlp_b1, mlp_w2, mlp_b2);
        }
    }
    final_kernel<<<CBS, blk, 0, stream>>>(slots, fin_w, fin_b, out0);
}

// Round 5
// 1965.824 us; speedup vs baseline: 1.4197x; 1.4197x over previous
//
#include <hip/hip_runtime.h>

// ---------------- problem constants ----------------
constexpr int CB   = 8;      // batch
constexpr int CN   = 1369;   // tokens (37*37)
constexpr int CDIN = 768;
constexpr int CS   = 7;      // slots
constexpr int CD   = 256;
constexpr int CITERS = 3;
constexpr int CRES = 37;
constexpr float CSIGMA = 5.0f;
constexpr int CBS = CB * CS;        // 56
constexpr int CRT = CBS * CN;       // 76664 rows for f_mlp
constexpr int CBN = CB * CN;        // 10952 rows for initial mlp
constexpr float LNEPS = 1e-5f;
constexpr float ATTN_EPS = 1e-8f;

typedef unsigned short u16;
typedef short bs8 __attribute__((ext_vector_type(8)));   // 8 bf16 (bit pattern in shorts)
typedef float f4 __attribute__((ext_vector_type(4)));

// ---------------- helpers ----------------
__device__ __forceinline__ float ag_x(int n) { return -1.f + (float)(n % CRES) * (2.f / 36.f); }
__device__ __forceinline__ float ag_y(int n) { return -1.f + (float)(n / CRES) * (2.f / 36.f); }

__device__ __forceinline__ u16 bf_rne(float f) {
    unsigned u = __float_as_uint(f);
    return (u16)((u + 0x7FFFu + ((u >> 16) & 1u)) >> 16);
}
__device__ __forceinline__ float bf_to_f(u16 h) { return __uint_as_float(((unsigned)h) << 16); }

// v = h + m + l with each plane bf16 (RNE); residual ~2^-27 relative
__device__ __forceinline__ void split3(float v, u16& h, u16& m, u16& l) {
    h = bf_rne(v); float r = v - bf_to_f(h);
    m = bf_rne(r); r -= bf_to_f(m);
    l = bf_rne(r);
}

// 256-thread block sum
__device__ __forceinline__ float block_reduce_sum(float v, float* sbuf) {
    #pragma unroll
    for (int off = 32; off > 0; off >>= 1) v += __shfl_down(v, off, 64);
    if ((threadIdx.x & 63) == 0) sbuf[threadIdx.x >> 6] = v;
    __syncthreads();
    if (threadIdx.x == 0) sbuf[0] = sbuf[0] + sbuf[1] + sbuf[2] + sbuf[3];
    __syncthreads();
    float r = sbuf[0];
    __syncthreads();
    return r;
}

// ---------------- layernorm (fp32 out) ----------------
__global__ __launch_bounds__(256) void ln_kernel(const float* __restrict__ in,
        float* __restrict__ out, const float* __restrict__ g,
        const float* __restrict__ b, int d) {
    __shared__ float sbuf[8];
    int row = blockIdx.x;
    const float* x = in + (size_t)row * d;
    float* y = out + (size_t)row * d;
    float s = 0.f;
    for (int i = threadIdx.x; i < d; i += 256) s += x[i];
    float mean = block_reduce_sum(s, sbuf) / d;
    float v = 0.f;
    for (int i = threadIdx.x; i < d; i += 256) { float t = x[i] - mean; v += t * t; }
    float var = block_reduce_sum(v, sbuf) / d;
    float rstd = rsqrtf(var + LNEPS);
    for (int i = threadIdx.x; i < d; i += 256) y[i] = (x[i] - mean) * rstd * g[i] + b[i];
}

// ---------------- transpose fp32 W[K][N] -> 3 bf16 planes Wt[N][K] ----------------
__global__ __launch_bounds__(256) void transpose_split3_kernel(const float* __restrict__ W,
        u16* __restrict__ Th, u16* __restrict__ Tm, u16* __restrict__ Tl, int K, int N) {
    __shared__ float tile[32][33];
    int nb = blockIdx.x * 32, kb = blockIdx.y * 32;
    int tx = threadIdx.x & 31, ty = threadIdx.x >> 5;   // ty 0..7
    #pragma unroll
    for (int i = 0; i < 32; i += 8)
        tile[ty + i][tx] = W[(size_t)(kb + ty + i) * N + nb + tx];
    __syncthreads();
    #pragma unroll
    for (int i = 0; i < 32; i += 8) {
        float v = tile[tx][ty + i];
        u16 h, m, l; split3(v, h, m, l);
        size_t idx = (size_t)(nb + ty + i) * K + kb + tx;
        Th[idx] = h; Tm[idx] = m; Tl[idx] = l;
    }
}

// ---------------- rel materialization (MUST use loop-entry S_p/S_s for both k and v paths) ----------------
__global__ __launch_bounds__(256) void rel_kernel(const float* __restrict__ S_p,
        const float* __restrict__ S_s, float* __restrict__ relv) {
    int r = blockIdx.x * 256 + threadIdx.x;
    if (r >= CRT) return;
    int bs = r / CN;
    int n = r - bs * CN;
    relv[2 * r]     = (ag_x(n) - S_p[2 * bs])     / (S_s[2 * bs]     * CSIGMA);
    relv[2 * r + 1] = (ag_y(n) - S_p[2 * bs + 1]) / (S_s[2 * bs + 1] * CSIGMA);
}

// ---------------- bf16 3-plane emulated-fp32 TN GEMM ----------------
// C[m][n] = act( sum_k A[m][k]*Bt[n][k] + bias[n] ), A fp32 (split on the fly),
// B pre-split into 3 bf16 planes. 6 MFMAs/tile: hh, mh, hm, mm, lh, hl.
// AMODE 0: A from fp32 array. AMODE 1: A built = KX[(b,n)][k] + rel0*gw0[k] + rel1*gw1[k] + gb[k]
//          (rel0/rel1 read from the relv buffer — loop-entry snapshot)
// EPI 0: store fp32. EPI 2: dots[m] += scale * C[m][:].q[bs(m)][:]. EPI 3: upd[bs(m)][n] += attn[m]*C[m][n]
template<int AMODE, int EPI>
__global__ __launch_bounds__(256)
void hgemm(const float* __restrict__ A,
           const u16* __restrict__ Bh, const u16* __restrict__ Bm, const u16* __restrict__ Bl,
           int M, int N, int K, const float* __restrict__ bias, int relu,
           float* __restrict__ Cf,
           const float* __restrict__ KXsrc, const float* __restrict__ relv,
           const float* __restrict__ gw, const float* __restrict__ gb,
           const float* __restrict__ qv, float* __restrict__ dots,
           const float* __restrict__ attn, float* __restrict__ upd) {
    constexpr int PK = 40;                       // padded K-stride (32 + 8)
    __shared__ short smem[6 * 128 * PK];         // 60 KB: Ah|Am|Al|Bh|Bm|Bl
    short* Ash = smem;
    short* Asm_ = smem + 128 * PK;
    short* Asl = smem + 2 * 128 * PK;
    short* Bsh = smem + 3 * 128 * PK;
    short* Bsm = smem + 4 * 128 * PK;
    short* Bsl = smem + 5 * 128 * PK;
    const int tid = threadIdx.x;
    const int m0 = blockIdx.x * 128, n0 = blockIdx.y * 128;
    const int w = tid >> 6, lane = tid & 63;
    const int wm = w & 1, wn = w >> 1;
    const int l15 = lane & 15, l4 = lane >> 4;
    const int sr = tid >> 2;                    // staging row 0..63
    const int sc = (tid & 3) * 8;               // staging col 0/8/16/24

    float r0[2], r1[2]; const float* asrc[2];
    #pragma unroll
    for (int it = 0; it < 2; it++) {
        int grow = m0 + sr + it * 64;
        int gcl = grow < M ? grow : M - 1;
        if constexpr (AMODE == 1) {
            int bs = gcl / CN;
            int n = gcl - bs * CN;
            int b = bs / CS;
            asrc[it] = KXsrc + (size_t)(b * CN + n) * CD + sc;
            r0[it] = relv[2 * gcl];
            r1[it] = relv[2 * gcl + 1];
        } else {
            asrc[it] = A + (size_t)gcl * K + sc;
        }
    }

    f4 acc[4][4];
    #pragma unroll
    for (int i = 0; i < 4; i++)
        #pragma unroll
        for (int j = 0; j < 4; j++) acc[i][j] = (f4){0.f, 0.f, 0.f, 0.f};

    for (int k0 = 0; k0 < K; k0 += 32) {
        #pragma unroll
        for (int it = 0; it < 2; it++) {
            int r = sr + it * 64;
            float v8[8];
            const float* p = asrc[it] + k0;
            *(float4*)&v8[0] = *(const float4*)(p);
            *(float4*)&v8[4] = *(const float4*)(p + 4);
            if constexpr (AMODE == 1) {
                float g0v[8], g1v[8], gbv[8];
                *(float4*)&g0v[0] = *(const float4*)(gw + k0 + sc);
                *(float4*)&g0v[4] = *(const float4*)(gw + k0 + sc + 4);
                *(float4*)&g1v[0] = *(const float4*)(gw + CD + k0 + sc);
                *(float4*)&g1v[4] = *(const float4*)(gw + CD + k0 + sc + 4);
                *(float4*)&gbv[0] = *(const float4*)(gb + k0 + sc);
                *(float4*)&gbv[4] = *(const float4*)(gb + k0 + sc + 4);
                #pragma unroll
                for (int j = 0; j < 8; j++)
                    v8[j] = v8[j] + r0[it] * g0v[j] + r1[it] * g1v[j] + gbv[j];
            }
            bs8 hv, mv, lv;
            #pragma unroll
            for (int j = 0; j < 8; j++) {
                u16 h, m, l; split3(v8[j], h, m, l);
                hv[j] = (short)h; mv[j] = (short)m; lv[j] = (short)l;
            }
            *(bs8*)(Ash  + r * PK + sc) = hv;
            *(bs8*)(Asm_ + r * PK + sc) = mv;
            *(bs8*)(Asl  + r * PK + sc) = lv;
            int nr = n0 + r;
            size_t bofs = (size_t)nr * K + k0 + sc;
            *(bs8*)(Bsh + r * PK + sc) = *(const bs8*)(Bh + bofs);
            *(bs8*)(Bsm + r * PK + sc) = *(const bs8*)(Bm + bofs);
            *(bs8*)(Bsl + r * PK + sc) = *(const bs8*)(Bl + bofs);
        }
        __syncthreads();
        bs8 ah[4], am[4], al_[4], bh[4], bm[4], bl[4];
        #pragma unroll
        for (int f = 0; f < 4; f++) {
            int ra = (wm * 64 + f * 16 + l15) * PK + l4 * 8;
            ah[f]  = *(const bs8*)(Ash  + ra);
            am[f]  = *(const bs8*)(Asm_ + ra);
            al_[f] = *(const bs8*)(Asl  + ra);
            int rb = (wn * 64 + f * 16 + l15) * PK + l4 * 8;
            bh[f] = *(const bs8*)(Bsh + rb);
            bm[f] = *(const bs8*)(Bsm + rb);
            bl[f] = *(const bs8*)(Bsl + rb);
        }
        #pragma unroll
        for (int mf = 0; mf < 4; mf++)
            #pragma unroll
            for (int nf = 0; nf < 4; nf++) {
                acc[mf][nf] = __builtin_amdgcn_mfma_f32_16x16x32_bf16(ah[mf],  bh[nf], acc[mf][nf], 0, 0, 0);
                acc[mf][nf] = __builtin_amdgcn_mfma_f32_16x16x32_bf16(am[mf],  bh[nf], acc[mf][nf], 0, 0, 0);
                acc[mf][nf] = __builtin_amdgcn_mfma_f32_16x16x32_bf16(ah[mf],  bm[nf], acc[mf][nf], 0, 0, 0);
                acc[mf][nf] = __builtin_amdgcn_mfma_f32_16x16x32_bf16(am[mf],  bm[nf], acc[mf][nf], 0, 0, 0);
                acc[mf][nf] = __builtin_amdgcn_mfma_f32_16x16x32_bf16(al_[mf], bh[nf], acc[mf][nf], 0, 0, 0);
                acc[mf][nf] = __builtin_amdgcn_mfma_f32_16x16x32_bf16(ah[mf],  bl[nf], acc[mf][nf], 0, 0, 0);
            }
        __syncthreads();
    }

    if constexpr (EPI == 0) {
        #pragma unroll
        for (int mf = 0; mf < 4; mf++)
            #pragma unroll
            for (int i = 0; i < 4; i++) {
                int grow = m0 + wm * 64 + mf * 16 + l4 * 4 + i;
                if (grow < M) {
                    #pragma unroll
                    for (int nf = 0; nf < 4; nf++) {
                        int col = n0 + wn * 64 + nf * 16 + l15;
                        float v = acc[mf][nf][i] + (bias ? bias[col] : 0.f);
                        if (relu) v = fmaxf(v, 0.f);
                        Cf[(size_t)grow * N + col] = v;
                    }
                }
            }
    } else if constexpr (EPI == 2) {
        float* red = (float*)smem;   // [128][32] = 16 KB
        #pragma unroll
        for (int mf = 0; mf < 4; mf++)
            #pragma unroll
            for (int i = 0; i < 4; i++) {
                int row_l = wm * 64 + mf * 16 + l4 * 4 + i;
                int grow = m0 + row_l;
                float p = 0.f;
                if (grow < M) {
                    int bs = grow / CN;
                    #pragma unroll
                    for (int nf = 0; nf < 4; nf++) {
                        int col = n0 + wn * 64 + nf * 16 + l15;
                        p += (acc[mf][nf][i] + bias[col]) * qv[bs * CD + col];
                    }
                }
                red[row_l * 32 + wn * 16 + l15] = p;
            }
        __syncthreads();
        if (tid < 128) {
            int grow = m0 + tid;
            if (grow < M) {
                float s = 0.f;
                #pragma unroll
                for (int c = 0; c < 32; c++) s += red[tid * 32 + c];
                atomicAdd(&dots[grow], s * 0.0625f);   // * D^-0.5
            }
        }
    } else {  // EPI == 3
        float* red = (float*)smem;   // [128][8]
        int bs0 = m0 / CN;
        int bnd = (bs0 + 1) * CN;
        for (int g = 0; g < 2; g++) {
            __syncthreads();
            #pragma unroll
            for (int nf = 0; nf < 4; nf++) {
                float s = 0.f;
                #pragma unroll
                for (int mf = 0; mf < 4; mf++)
                    #pragma unroll
                    for (int i = 0; i < 4; i++) {
                        int grow = m0 + wm * 64 + mf * 16 + l4 * 4 + i;
                        int gg = grow >= bnd ? 1 : 0;
                        if (grow < M && gg == g) {
                            int col = n0 + wn * 64 + nf * 16 + l15;
                            s += (acc[mf][nf][i] + bias[col]) * attn[grow];
                        }
                    }
                int col_l = wn * 64 + nf * 16 + l15;
                red[col_l * 8 + wm * 4 + l4] = s;
            }
            __syncthreads();
            if (tid < 128) {
                int bsg = bs0 + g;
                if (bsg < CBS) {
                    float s = 0.f;
                    #pragma unroll
                    for (int c = 0; c < 8; c++) s += red[tid * 8 + c];
                    atomicAdd(&upd[bsg * CD + n0 + tid], s);
                }
            }
        }
    }
}

// ---------------- small kernels ----------------
__global__ __launch_bounds__(256) void init_kernel(const float* __restrict__ slots_init_p,
        const float* __restrict__ S_s0, const float* __restrict__ S_p0,
        float* __restrict__ slots, float* __restrict__ S_s, float* __restrict__ S_p) {
    int bs = blockIdx.x, t = threadIdx.x;
    int s = bs % CS;
    slots[bs * CD + t] = slots_init_p[s * CD + t];
    if (t < 2) { S_s[bs * 2 + t] = S_s0[s * 2 + t]; S_p[bs * 2 + t] = S_p0[s * 2 + t]; }
}

__global__ __launch_bounds__(256) void slots_q_kernel(const float* __restrict__ slots,
        const float* __restrict__ ln_g, const float* __restrict__ ln_b,
        const float* __restrict__ Wq, float* __restrict__ q) {
    __shared__ float sn[CD];
    __shared__ float sbuf[8];
    int row = blockIdx.x, t = threadIdx.x;
    float x = slots[row * CD + t];
    float mean = block_reduce_sum(x, sbuf) / CD;
    float d0 = x - mean;
    float var = block_reduce_sum(d0 * d0, sbuf) / CD;
    sn[t] = d0 * rsqrtf(var + LNEPS) * ln_g[t] + ln_b[t];
    __syncthreads();
    float acc = 0.f;
    for (int j = 0; j < CD; j++) acc += sn[j] * Wq[j * CD + t];
    q[row * CD + t] = acc;
}

__global__ __launch_bounds__(256) void softmax_kernel(float* __restrict__ dots) {
    int idx = blockIdx.x * 256 + threadIdx.x;
    if (idx >= CBN) return;
    int b = idx / CN, n = idx - b * CN;
    float v[CS]; float mx = -1e30f;
    #pragma unroll
    for (int s = 0; s < CS; s++) { v[s] = dots[(size_t)(b * CS + s) * CN + n]; mx = fmaxf(mx, v[s]); }
    float sum = 0.f;
    #pragma unroll
    for (int s = 0; s < CS; s++) { v[s] = __expf(v[s] - mx); sum += v[s]; }
    float inv = 1.f / sum;
    #pragma unroll
    for (int s = 0; s < CS; s++) dots[(size_t)(b * CS + s) * CN + n] = v[s] * inv + ATTN_EPS;
}

__global__ __launch_bounds__(256) void attn_moments_kernel(float* __restrict__ u,
        float* __restrict__ S_p, float* __restrict__ S_s) {
    __shared__ float sbuf[8];
    int bs = blockIdx.x;
    float* up = u + (size_t)bs * CN;
    float m0 = 0, m1x = 0, m1y = 0, m2x = 0, m2y = 0;
    for (int n = threadIdx.x; n < CN; n += 256) {
        float uu = up[n];
        float ax = ag_x(n), ay = ag_y(n);
        m0 += uu; m1x += uu * ax; m1y += uu * ay; m2x += uu * ax * ax; m2y += uu * ay * ay;
    }
    m0  = block_reduce_sum(m0, sbuf);
    m1x = block_reduce_sum(m1x, sbuf);
    m1y = block_reduce_sum(m1y, sbuf);
    m2x = block_reduce_sum(m2x, sbuf);
    m2y = block_reduce_sum(m2y, sbuf);
    float px = m1x / m0, py = m1y / m0;
    if (threadIdx.x == 0) {
        S_p[2 * bs] = px; S_p[2 * bs + 1] = py;
        S_s[2 * bs]     = sqrtf(fmaxf(m2x / m0 - px * px, 0.f));
        S_s[2 * bs + 1] = sqrtf(fmaxf(m2y / m0 - py * py, 0.f));
    }
    float inv = 1.f / m0;
    for (int n = threadIdx.x; n < CN; n += 256) up[n] = up[n] * inv;   // in-place normalize
}

__global__ __launch_bounds__(256) void gru_mlp_kernel(const float* __restrict__ upd,
        float* __restrict__ slots,
        const float* __restrict__ wih, const float* __restrict__ whh,
        const float* __restrict__ bih, const float* __restrict__ bhh,
        const float* __restrict__ mg, const float* __restrict__ mb,
        const float* __restrict__ w1, const float* __restrict__ b1,
        const float* __restrict__ w2, const float* __restrict__ b2) {
    __shared__ float sU[CD], sH[CD], sM[CD], sH1[4 * CD];
    __shared__ float sbuf[8];
    int row = blockIdx.x, t = threadIdx.x;
    sU[t] = upd[row * CD + t];
    sH[t] = slots[row * CD + t];
    __syncthreads();
    float gi0 = bih[t], gi1 = bih[CD + t], gi2 = bih[2 * CD + t];
    float gh0 = bhh[t], gh1 = bhh[CD + t], gh2 = bhh[2 * CD + t];
    for (int j = 0; j < CD; j++) {
        float uj = sU[j], hj = sH[j];
        gi0 += uj * wih[j * 3 * CD + t];
        gi1 += uj * wih[j * 3 * CD + CD + t];
        gi2 += uj * wih[j * 3 * CD + 2 * CD + t];
        gh0 += hj * whh[j * 3 * CD + t];
        gh1 += hj * whh[j * 3 * CD + CD + t];
        gh2 += hj * whh[j * 3 * CD + 2 * CD + t];
    }
    float r = 1.f / (1.f + expf(-(gi0 + gh0)));
    float z = 1.f / (1.f + expf(-(gi1 + gh1)));
    float nn = tanhf(gi2 + r * gh2);
    float hprev = sH[t];
    float snew = (1.f - z) * nn + z * hprev;
    float mean = block_reduce_sum(snew, sbuf) / CD;
    float dv = snew - mean;
    float var = block_reduce_sum(dv * dv, sbuf) / CD;
    sM[t] = dv * rsqrtf(var + LNEPS) * mg[t] + mb[t];
    __syncthreads();
    #pragma unroll
    for (int o = 0; o < 4; o++) {
        int c = t + o * 256;
        float a = b1[c];
        for (int j = 0; j < CD; j++) a += sM[j] * w1[j * 4 * CD + c];
        sH1[c] = fmaxf(a, 0.f);
    }
    __syncthreads();
    float out = b2[t];
    for (int j = 0; j < 4 * CD; j++) out += sH1[j] * w2[j * CD + t];
    slots[row * CD + t] = snew + out;
}

__global__ __launch_bounds__(256) void final_kernel(const float* __restrict__ slots,
        const float* __restrict__ fw, const float* __restrict__ fb, float* __restrict__ out) {
    __shared__ float sS[CD];
    int row = blockIdx.x, t = threadIdx.x;
    sS[t] = slots[row * CD + t];
    __syncthreads();
    float a = fb[t];
    for (int j = 0; j < CD; j++) a += sS[j] * fw[j * CD + t];
    out[row * CD + t] = a;
}

// ---------------- launcher ----------------
extern "C" void kernel_launch(void* const* d_in, const int* in_sizes, int n_in,
                              void* d_out, int out_size, void* d_ws, size_t ws_size,
                              hipStream_t stream) {
    (void)in_sizes; (void)n_in; (void)out_size;
    const float* inputs       = (const float*)d_in[0];
    const float* slots_init_p = (const float*)d_in[1];
    const float* S_s0         = (const float*)d_in[2];
    const float* S_p0         = (const float*)d_in[3];
    const float* im_ln1_g = (const float*)d_in[4];
    const float* im_ln1_b = (const float*)d_in[5];
    const float* im_w1    = (const float*)d_in[6];
    const float* im_b1    = (const float*)d_in[7];
    const float* im_w2    = (const float*)d_in[8];
    const float* im_b2    = (const float*)d_in[9];
    const float* im_ln2_g = (const float*)d_in[10];
    const float* im_ln2_b = (const float*)d_in[11];
    const float* Wq  = (const float*)d_in[12];
    const float* Wk  = (const float*)d_in[13];
    const float* Wv  = (const float*)d_in[14];
    const float* g_w = (const float*)d_in[15];
    const float* g_b = (const float*)d_in[16];
    const float* f_w1 = (const float*)d_in[17];
    const float* f_b1 = (const float*)d_in[18];
    const float* f_w2 = (const float*)d_in[19];
    const float* f_b2 = (const float*)d_in[20];
    const float* ln_g = (const float*)d_in[21];
    const float* ln_b = (const float*)d_in[22];
    const float* gru_wih = (const float*)d_in[23];
    const float* gru_whh = (const float*)d_in[24];
    const float* gru_bih = (const float*)d_in[25];
    const float* gru_bhh = (const float*)d_in[26];
    const float* mlp_ln_g = (const float*)d_in[27];
    const float* mlp_ln_b = (const float*)d_in[28];
    const float* mlp_w1 = (const float*)d_in[29];
    const float* mlp_b1 = (const float*)d_in[30];
    const float* mlp_w2 = (const float*)d_in[31];
    const float* mlp_b2 = (const float*)d_in[32];
    const float* fin_w = (const float*)d_in[33];
    const float* fin_b = (const float*)d_in[34];

    float* ws0 = (float*)d_ws;
    const size_t H_FL = (size_t)CRT * CD;           // 19,625,984 floats
    float* H = ws0;
    // aliases inside H (init phase only; H first written in the loop)
    float* xln = H;                                  // CBN*CDIN = 8,411,136 fl
    float* X1  = H + (size_t)CBN * CDIN;             // ends 16,822,272 fl
    u16* w1th = (u16*)(H + 16822272);                // 3 planes x 589,824 u16
    u16* w1tm = w1th + (size_t)CDIN * CDIN;
    u16* w1tl = w1tm + (size_t)CDIN * CDIN;          // ends fl 17,707,008
    u16* w2th = (u16*)(H + 17707008);                // 3 x 196,608 u16
    u16* w2tm = w2th + (size_t)CDIN * CD;
    u16* w2tl = w2tm + (size_t)CDIN * CD;            // ends fl 18,001,920
    u16* wkth = (u16*)(H + 18001920);                // 3 x 65,536
    u16* wktm = wkth + (size_t)CD * CD;
    u16* wktl = wktm + (size_t)CD * CD;              // ends fl 18,100,224
    u16* wvth = (u16*)(H + 18100224);
    u16* wvtm = wvth + (size_t)CD * CD;
    u16* wvtl = wvtm + (size_t)CD * CD;              // ends fl 18,198,528 <= 19,625,984  OK
    float* xDn = H;                                  // CBN*CD fl, reuses xln space (dead)

    char* base = (char*)(ws0 + H_FL);
    size_t off = 0;
    auto take = [&](size_t bytes) { void* p = base + off; off += (bytes + 255) & ~(size_t)255; return p; };
    float* KXb = (float*)take((size_t)CBN * CD * 4);
    float* VXb = (float*)take((size_t)CBN * CD * 4);
    float* relv = (float*)take((size_t)CRT * 2 * 4);   // loop-entry rel snapshot
    u16* fw1h = (u16*)take((size_t)CD * CD * 2);
    u16* fw1m = (u16*)take((size_t)CD * CD * 2);
    u16* fw1l = (u16*)take((size_t)CD * CD * 2);
    u16* fw2h = (u16*)take((size_t)CD * CD * 2);
    u16* fw2m = (u16*)take((size_t)CD * CD * 2);
    u16* fw2l = (u16*)take((size_t)CD * CD * 2);
    float* qb    = (float*)take((size_t)CBS * CD * 4);
    float* S_pb  = (float*)take((size_t)CBS * 2 * 4);
    float* S_sb  = (float*)take((size_t)CBS * 2 * 4);
    float* slots = (float*)take((size_t)CBS * CD * 4);
    float* upd   = (float*)take((size_t)CBS * CD * 4);
    size_t need = H_FL * 4 + off;
    if (ws_size < need) return;   // insufficient workspace (same behavior every call)

    float* out0 = (float*)d_out;            // [CBS,CD]
    float* attnb = out0 + CBS * CD;         // [CBS,CN] — doubles as dots buffer

    dim3 blk(256);
    const int gM_bn = (CBN + 127) / 128;    // 86
    const int gM_rt = (CRT + 127) / 128;    // 599
    const float* NUL = nullptr;

    // ---- weight transposes + splits (outputs live inside H, used only in init phase except fw1/fw2) ----
    transpose_split3_kernel<<<dim3(CDIN/32, CDIN/32), blk, 0, stream>>>(im_w1, w1th, w1tm, w1tl, CDIN, CDIN);
    transpose_split3_kernel<<<dim3(CD/32,   CDIN/32), blk, 0, stream>>>(im_w2, w2th, w2tm, w2tl, CDIN, CD);
    transpose_split3_kernel<<<dim3(CD/32,   CD/32),   blk, 0, stream>>>(Wk,   wkth, wktm, wktl, CD, CD);
    transpose_split3_kernel<<<dim3(CD/32,   CD/32),   blk, 0, stream>>>(Wv,   wvth, wvtm, wvtl, CD, CD);
    transpose_split3_kernel<<<dim3(CD/32,   CD/32),   blk, 0, stream>>>(f_w1, fw1h, fw1m, fw1l, CD, CD);
    transpose_split3_kernel<<<dim3(CD/32,   CD/32),   blk, 0, stream>>>(f_w2, fw2h, fw2m, fw2l, CD, CD);

    // ---- initial mlp (all activations fp32; split3 on the fly inside hgemm) ----
    ln_kernel<<<CBN, blk, 0, stream>>>(inputs, xln, im_ln1_g, im_ln1_b, CDIN);
    hgemm<0,0><<<dim3(gM_bn, CDIN/128), blk, 0, stream>>>(xln, w1th, w1tm, w1tl, CBN, CDIN, CDIN,
        im_b1, 1, X1, NUL, NUL, NUL, NUL, NUL, nullptr, NUL, nullptr);
    hgemm<0,0><<<dim3(gM_bn, CD/128), blk, 0, stream>>>(X1, w2th, w2tm, w2tl, CBN, CD, CDIN,
        im_b2, 0, KXb, NUL, NUL, NUL, NUL, NUL, nullptr, NUL, nullptr);   // xD -> KXb
    ln_kernel<<<CBN, blk, 0, stream>>>(KXb, xDn, im_ln2_g, im_ln2_b, CD);
    hgemm<0,0><<<dim3(gM_bn, CD/128), blk, 0, stream>>>(xDn, wkth, wktm, wktl, CBN, CD, CD,
        nullptr, 0, KXb, NUL, NUL, NUL, NUL, NUL, nullptr, NUL, nullptr);
    hgemm<0,0><<<dim3(gM_bn, CD/128), blk, 0, stream>>>(xDn, wvth, wvtm, wvtl, CBN, CD, CD,
        nullptr, 0, VXb, NUL, NUL, NUL, NUL, NUL, nullptr, NUL, nullptr);
    init_kernel<<<CBS, blk, 0, stream>>>(slots_init_p, S_s0, S_p0, slots, S_sb, S_pb);

    for (int t = 0; t <= CITERS; t++) {
        slots_q_kernel<<<CBS, blk, 0, stream>>>(slots, ln_g, ln_b, Wq, qb);
        // rel snapshot from loop-entry S_p/S_s — used by BOTH k and v paths this iteration
        rel_kernel<<<(CRT + 255) / 256, blk, 0, stream>>>(S_pb, S_sb, relv);
        // k path: H = relu((KX + rel@g_w + g_b) @ f_w1 + f_b1), A built on the fly
        hgemm<1,0><<<dim3(gM_rt, CD/128), blk, 0, stream>>>(NUL, fw1h, fw1m, fw1l, CRT, CD, CD,
            f_b1, 1, H, KXb, relv, g_w, g_b, NUL, nullptr, NUL, nullptr);
        hipMemsetAsync(attnb, 0, (size_t)CRT * sizeof(float), stream);
        hgemm<0,2><<<dim3(gM_rt, CD/128), blk, 0, stream>>>(H, fw2h, fw2m, fw2l, CRT, CD, CD,
            f_b2, 0, nullptr, NUL, NUL, NUL, NUL, qb, attnb, NUL, nullptr);
        softmax_kernel<<<(CBN + 255) / 256, blk, 0, stream>>>(attnb);
        attn_moments_kernel<<<CBS, blk, 0, stream>>>(attnb, S_pb, S_sb);
        if (t < CITERS) {
            hgemm<1,0><<<dim3(gM_rt, CD/128), blk, 0, stream>>>(NUL, fw1h, fw1m, fw1l, CRT, CD, CD,
                f_b1, 1, H, VXb, relv, g_w, g_b, NUL, nullptr, NUL, nullptr);
            hipMemsetAsync(upd, 0, (size_t)CBS * CD * sizeof(float), stream);
            hgemm<0,3><<<dim3(gM_rt, CD/128), blk, 0, stream>>>(H, fw2h, fw2m, fw2l, CRT, CD, CD,
                f_b2, 0, nullptr, NUL, NUL, NUL, NUL, NUL, nullptr, attnb, upd);
            gru_mlp_kernel<<<CBS, blk, 0, stream>>>(upd, slots, gru_wih, gru_whh, gru_bih, gru_bhh,
                mlp_ln_g, mlp_ln_b, mlp_w1, mlp_b1, mlp_w2, mlp_b2);
        }
    }
    final_kernel<<<CBS, blk, 0, stream>>>(slots, fin_w, fin_b, out0);
}

// Round 6
// 1435.897 us; speedup vs baseline: 1.9437x; 1.3691x over previous
//
#include <hip/hip_runtime.h>

// ---------------- problem constants ----------------
constexpr int CB   = 8;      // batch
constexpr int CN   = 1369;   // tokens (37*37)
constexpr int CDIN = 768;
constexpr int CS   = 7;      // slots
constexpr int CD   = 256;
constexpr int CITERS = 3;
constexpr int CRES = 37;
constexpr float CSIGMA = 5.0f;
constexpr int CBS = CB * CS;        // 56
constexpr int CRT = CBS * CN;       // 76664 rows for f_mlp
constexpr int CBN = CB * CN;        // 10952 rows for initial mlp
constexpr float LNEPS = 1e-5f;
constexpr float ATTN_EPS = 1e-8f;

typedef unsigned short u16;
typedef short bs8 __attribute__((ext_vector_type(8)));   // 8 bf16 (bit pattern in shorts)
typedef float f4 __attribute__((ext_vector_type(4)));

// ---------------- helpers ----------------
__device__ __forceinline__ float ag_x(int n) { return -1.f + (float)(n % CRES) * (2.f / 36.f); }
__device__ __forceinline__ float ag_y(int n) { return -1.f + (float)(n / CRES) * (2.f / 36.f); }

__device__ __forceinline__ u16 bf_rne(float f) {
    unsigned u = __float_as_uint(f);
    return (u16)((u + 0x7FFFu + ((u >> 16) & 1u)) >> 16);
}
__device__ __forceinline__ float bf_to_f(u16 h) { return __uint_as_float(((unsigned)h) << 16); }

// v = h + m + l with each plane bf16 (RNE); residual ~2^-27 relative
__device__ __forceinline__ void split3(float v, u16& h, u16& m, u16& l) {
    h = bf_rne(v); float r = v - bf_to_f(h);
    m = bf_rne(r); r -= bf_to_f(m);
    l = bf_rne(r);
}

// 256-thread block sum
__device__ __forceinline__ float block_reduce_sum(float v, float* sbuf) {
    #pragma unroll
    for (int off = 32; off > 0; off >>= 1) v += __shfl_down(v, off, 64);
    if ((threadIdx.x & 63) == 0) sbuf[threadIdx.x >> 6] = v;
    __syncthreads();
    if (threadIdx.x == 0) sbuf[0] = sbuf[0] + sbuf[1] + sbuf[2] + sbuf[3];
    __syncthreads();
    float r = sbuf[0];
    __syncthreads();
    return r;
}

// ---------------- layernorm (fp32 out) ----------------
__global__ __launch_bounds__(256) void ln_kernel(const float* __restrict__ in,
        float* __restrict__ out, const float* __restrict__ g,
        const float* __restrict__ b, int d) {
    __shared__ float sbuf[8];
    int row = blockIdx.x;
    const float* x = in + (size_t)row * d;
    float* y = out + (size_t)row * d;
    float s = 0.f;
    for (int i = threadIdx.x; i < d; i += 256) s += x[i];
    float mean = block_reduce_sum(s, sbuf) / d;
    float v = 0.f;
    for (int i = threadIdx.x; i < d; i += 256) { float t = x[i] - mean; v += t * t; }
    float var = block_reduce_sum(v, sbuf) / d;
    float rstd = rsqrtf(var + LNEPS);
    for (int i = threadIdx.x; i < d; i += 256) y[i] = (x[i] - mean) * rstd * g[i] + b[i];
}

// ---------------- transpose fp32 W[K][N] -> 3 bf16 planes Wt[N][K] ----------------
__global__ __launch_bounds__(256) void transpose_split3_kernel(const float* __restrict__ W,
        u16* __restrict__ Th, u16* __restrict__ Tm, u16* __restrict__ Tl, int K, int N) {
    __shared__ float tile[32][33];
    int nb = blockIdx.x * 32, kb = blockIdx.y * 32;
    int tx = threadIdx.x & 31, ty = threadIdx.x >> 5;   // ty 0..7
    #pragma unroll
    for (int i = 0; i < 32; i += 8)
        tile[ty + i][tx] = W[(size_t)(kb + ty + i) * N + nb + tx];
    __syncthreads();
    #pragma unroll
    for (int i = 0; i < 32; i += 8) {
        float v = tile[tx][ty + i];
        u16 h, m, l; split3(v, h, m, l);
        size_t idx = (size_t)(nb + ty + i) * K + kb + tx;
        Th[idx] = h; Tm[idx] = m; Tl[idx] = l;
    }
}

// ---------------- small fp32 weight-product: P[k][n] = sum_j A[k][j]*B[j][n], all [256][256] ----------------
__global__ __launch_bounds__(256) void wprod_kernel(const float* __restrict__ A,
        const float* __restrict__ B, float* __restrict__ P) {
    __shared__ float arow[CD];
    int k = blockIdx.x, n = threadIdx.x;
    arow[n] = A[k * CD + n];
    __syncthreads();
    float acc = 0.f;
    for (int j = 0; j < CD; j++) acc += arow[j] * B[j * CD + n];
    P[k * CD + n] = acc;
}

// G2[g][n] = sum_j g_w[g][j]*f_w1[j][n];  gb1[n] = sum_j g_b[j]*f_w1[j][n] + f_b1[n]
__global__ __launch_bounds__(256) void g2_kernel(const float* __restrict__ g_w,
        const float* __restrict__ g_b, const float* __restrict__ f_w1,
        const float* __restrict__ f_b1, float* __restrict__ G2, float* __restrict__ gb1) {
    int n = threadIdx.x;
    float a0 = 0.f, a1 = 0.f, ab = 0.f;
    for (int j = 0; j < CD; j++) {
        float w = f_w1[j * CD + n];
        a0 += g_w[j] * w;
        a1 += g_w[CD + j] * w;
        ab += g_b[j] * w;
    }
    G2[n] = a0; G2[CD + n] = a1; gb1[n] = ab + f_b1[n];
}

// ---------------- rel materialization (loop-entry S_p/S_s snapshot, shared by k and v paths) ----------------
__global__ __launch_bounds__(256) void rel_kernel(const float* __restrict__ S_p,
        const float* __restrict__ S_s, float* __restrict__ relv) {
    int r = blockIdx.x * 256 + threadIdx.x;
    if (r >= CRT) return;
    int bs = r / CN;
    int n = r - bs * CN;
    relv[2 * r]     = (ag_x(n) - S_p[2 * bs])     / (S_s[2 * bs]     * CSIGMA);
    relv[2 * r + 1] = (ag_y(n) - S_p[2 * bs + 1]) / (S_s[2 * bs + 1] * CSIGMA);
}

// ---------------- bf16 3-plane emulated-fp32 TN GEMM ----------------
// AMODE 0: A from fp32 array [M][K].
// AMODE 2: A built = relu( SRC[(b,n)][k] + r0*G2[0][k] + r1*G2[1][k] + gb1[k] )  (fused f_mlp layer-1,
//          r0/r1 from relv — loop-entry snapshot; SRC = KXW1 or VXW1)
// EPI 0: store fp32. EPI 2: dots[m] += scale * C[m][:].q[bs(m)][:]. EPI 3: upd[bs(m)][n] += attn[m]*C[m][n]
template<int AMODE, int EPI>
__global__ __launch_bounds__(256)
void hgemm(const float* __restrict__ A,
           const u16* __restrict__ Bh, const u16* __restrict__ Bm, const u16* __restrict__ Bl,
           int M, int N, int K, const float* __restrict__ bias, int relu,
           float* __restrict__ Cf,
           const float* __restrict__ SRC, const float* __restrict__ relv,
           const float* __restrict__ gw, const float* __restrict__ gb,
           const float* __restrict__ qv, float* __restrict__ dots,
           const float* __restrict__ attn, float* __restrict__ upd) {
    constexpr int PK = 40;                       // padded K-stride (32 + 8)
    __shared__ short smem[6 * 128 * PK];         // 60 KB: Ah|Am|Al|Bh|Bm|Bl
    short* Ash = smem;
    short* Asm_ = smem + 128 * PK;
    short* Asl = smem + 2 * 128 * PK;
    short* Bsh = smem + 3 * 128 * PK;
    short* Bsm = smem + 4 * 128 * PK;
    short* Bsl = smem + 5 * 128 * PK;
    const int tid = threadIdx.x;
    const int m0 = blockIdx.x * 128, n0 = blockIdx.y * 128;
    const int w = tid >> 6, lane = tid & 63;
    const int wm = w & 1, wn = w >> 1;
    const int l15 = lane & 15, l4 = lane >> 4;
    const int sr = tid >> 2;                    // staging row 0..63
    const int sc = (tid & 3) * 8;               // staging col 0/8/16/24

    float r0[2], r1[2]; const float* asrc[2];
    #pragma unroll
    for (int it = 0; it < 2; it++) {
        int grow = m0 + sr + it * 64;
        int gcl = grow < M ? grow : M - 1;
        if constexpr (AMODE == 2) {
            int bs = gcl / CN;
            int n = gcl - bs * CN;
            int b = bs / CS;
            asrc[it] = SRC + (size_t)(b * CN + n) * CD + sc;
            r0[it] = relv[2 * gcl];
            r1[it] = relv[2 * gcl + 1];
        } else {
            asrc[it] = A + (size_t)gcl * K + sc;
        }
    }

    f4 acc[4][4];
    #pragma unroll
    for (int i = 0; i < 4; i++)
        #pragma unroll
        for (int j = 0; j < 4; j++) acc[i][j] = (f4){0.f, 0.f, 0.f, 0.f};

    for (int k0 = 0; k0 < K; k0 += 32) {
        #pragma unroll
        for (int it = 0; it < 2; it++) {
            int r = sr + it * 64;
            float v8[8];
            const float* p = asrc[it] + k0;
            *(float4*)&v8[0] = *(const float4*)(p);
            *(float4*)&v8[4] = *(const float4*)(p + 4);
            if constexpr (AMODE == 2) {
                float g0v[8], g1v[8], gbv[8];
                *(float4*)&g0v[0] = *(const float4*)(gw + k0 + sc);
                *(float4*)&g0v[4] = *(const float4*)(gw + k0 + sc + 4);
                *(float4*)&g1v[0] = *(const float4*)(gw + CD + k0 + sc);
                *(float4*)&g1v[4] = *(const float4*)(gw + CD + k0 + sc + 4);
                *(float4*)&gbv[0] = *(const float4*)(gb + k0 + sc);
                *(float4*)&gbv[4] = *(const float4*)(gb + k0 + sc + 4);
                #pragma unroll
                for (int j = 0; j < 8; j++)
                    v8[j] = fmaxf(v8[j] + r0[it] * g0v[j] + r1[it] * g1v[j] + gbv[j], 0.f);
            }
            bs8 hv, mv, lv;
            #pragma unroll
            for (int j = 0; j < 8; j++) {
                u16 h, m, l; split3(v8[j], h, m, l);
                hv[j] = (short)h; mv[j] = (short)m; lv[j] = (short)l;
            }
            *(bs8*)(Ash  + r * PK + sc) = hv;
            *(bs8*)(Asm_ + r * PK + sc) = mv;
            *(bs8*)(Asl  + r * PK + sc) = lv;
            int nr = n0 + r;
            size_t bofs = (size_t)nr * K + k0 + sc;
            *(bs8*)(Bsh + r * PK + sc) = *(const bs8*)(Bh + bofs);
            *(bs8*)(Bsm + r * PK + sc) = *(const bs8*)(Bm + bofs);
            *(bs8*)(Bsl + r * PK + sc) = *(const bs8*)(Bl + bofs);
        }
        __syncthreads();
        bs8 ah[4], am[4], al_[4], bh[4], bm[4], bl[4];
        #pragma unroll
        for (int f = 0; f < 4; f++) {
            int ra = (wm * 64 + f * 16 + l15) * PK + l4 * 8;
            ah[f]  = *(const bs8*)(Ash  + ra);
            am[f]  = *(const bs8*)(Asm_ + ra);
            al_[f] = *(const bs8*)(Asl  + ra);
            int rb = (wn * 64 + f * 16 + l15) * PK + l4 * 8;
            bh[f] = *(const bs8*)(Bsh + rb);
            bm[f] = *(const bs8*)(Bsm + rb);
            bl[f] = *(const bs8*)(Bsl + rb);
        }
        #pragma unroll
        for (int mf = 0; mf < 4; mf++)
            #pragma unroll
            for (int nf = 0; nf < 4; nf++) {
                acc[mf][nf] = __builtin_amdgcn_mfma_f32_16x16x32_bf16(ah[mf],  bh[nf], acc[mf][nf], 0, 0, 0);
                acc[mf][nf] = __builtin_amdgcn_mfma_f32_16x16x32_bf16(am[mf],  bh[nf], acc[mf][nf], 0, 0, 0);
                acc[mf][nf] = __builtin_amdgcn_mfma_f32_16x16x32_bf16(ah[mf],  bm[nf], acc[mf][nf], 0, 0, 0);
                acc[mf][nf] = __builtin_amdgcn_mfma_f32_16x16x32_bf16(am[mf],  bm[nf], acc[mf][nf], 0, 0, 0);
                acc[mf][nf] = __builtin_amdgcn_mfma_f32_16x16x32_bf16(al_[mf], bh[nf], acc[mf][nf], 0, 0, 0);
                acc[mf][nf] = __builtin_amdgcn_mfma_f32_16x16x32_bf16(ah[mf],  bl[nf], acc[mf][nf], 0, 0, 0);
            }
        __syncthreads();
    }

    if constexpr (EPI == 0) {
        #pragma unroll
        for (int mf = 0; mf < 4; mf++)
            #pragma unroll
            for (int i = 0; i < 4; i++) {
                int grow = m0 + wm * 64 + mf * 16 + l4 * 4 + i;
                if (grow < M) {
                    #pragma unroll
                    for (int nf = 0; nf < 4; nf++) {
                        int col = n0 + wn * 64 + nf * 16 + l15;
                        float v = acc[mf][nf][i] + (bias ? bias[col] : 0.f);
                        if (relu) v = fmaxf(v, 0.f);
                        Cf[(size_t)grow * N + col] = v;
                    }
                }
            }
    } else if constexpr (EPI == 2) {
        float* red = (float*)smem;   // [128][32] = 16 KB
        #pragma unroll
        for (int mf = 0; mf < 4; mf++)
            #pragma unroll
            for (int i = 0; i < 4; i++) {
                int row_l = wm * 64 + mf * 16 + l4 * 4 + i;
                int grow = m0 + row_l;
                float p = 0.f;
                if (grow < M) {
                    int bs = grow / CN;
                    #pragma unroll
                    for (int nf = 0; nf < 4; nf++) {
                        int col = n0 + wn * 64 + nf * 16 + l15;
                        p += (acc[mf][nf][i] + bias[col]) * qv[bs * CD + col];
                    }
                }
                red[row_l * 32 + wn * 16 + l15] = p;
            }
        __syncthreads();
        if (tid < 128) {
            int grow = m0 + tid;
            if (grow < M) {
                float s = 0.f;
                #pragma unroll
                for (int c = 0; c < 32; c++) s += red[tid * 32 + c];
                atomicAdd(&dots[grow], s * 0.0625f);   // * D^-0.5
            }
        }
    } else {  // EPI == 3
        float* red = (float*)smem;   // [128][8]
        int bs0 = m0 / CN;
        int bnd = (bs0 + 1) * CN;
        for (int g = 0; g < 2; g++) {
            __syncthreads();
            #pragma unroll
            for (int nf = 0; nf < 4; nf++) {
                float s = 0.f;
                #pragma unroll
                for (int mf = 0; mf < 4; mf++)
                    #pragma unroll
                    for (int i = 0; i < 4; i++) {
                        int grow = m0 + wm * 64 + mf * 16 + l4 * 4 + i;
                        int gg = grow >= bnd ? 1 : 0;
                        if (grow < M && gg == g) {
                            int col = n0 + wn * 64 + nf * 16 + l15;
                            s += (acc[mf][nf][i] + bias[col]) * attn[grow];
                        }
                    }
                int col_l = wn * 64 + nf * 16 + l15;
                red[col_l * 8 + wm * 4 + l4] = s;
            }
            __syncthreads();
            if (tid < 128) {
                int bsg = bs0 + g;
                if (bsg < CBS) {
                    float s = 0.f;
                    #pragma unroll
                    for (int c = 0; c < 8; c++) s += red[tid * 8 + c];
                    atomicAdd(&upd[bsg * CD + n0 + tid], s);
                }
            }
        }
    }
}

// ---------------- small kernels ----------------
__global__ __launch_bounds__(256) void init_kernel(const float* __restrict__ slots_init_p,
        const float* __restrict__ S_s0, const float* __restrict__ S_p0,
        float* __restrict__ slots, float* __restrict__ S_s, float* __restrict__ S_p) {
    int bs = blockIdx.x, t = threadIdx.x;
    int s = bs % CS;
    slots[bs * CD + t] = slots_init_p[s * CD + t];
    if (t < 2) { S_s[bs * 2 + t] = S_s0[s * 2 + t]; S_p[bs * 2 + t] = S_p0[s * 2 + t]; }
}

__global__ __launch_bounds__(256) void slots_q_kernel(const float* __restrict__ slots,
        const float* __restrict__ ln_g, const float* __restrict__ ln_b,
        const float* __restrict__ Wq, float* __restrict__ q) {
    __shared__ float sn[CD];
    __shared__ float sbuf[8];
    int row = blockIdx.x, t = threadIdx.x;
    float x = slots[row * CD + t];
    float mean = block_reduce_sum(x, sbuf) / CD;
    float d0 = x - mean;
    float var = block_reduce_sum(d0 * d0, sbuf) / CD;
    sn[t] = d0 * rsqrtf(var + LNEPS) * ln_g[t] + ln_b[t];
    __syncthreads();
    float acc = 0.f;
    for (int j = 0; j < CD; j++) acc += sn[j] * Wq[j * CD + t];
    q[row * CD + t] = acc;
}

__global__ __launch_bounds__(256) void softmax_kernel(float* __restrict__ dots) {
    int idx = blockIdx.x * 256 + threadIdx.x;
    if (idx >= CBN) return;
    int b = idx / CN, n = idx - b * CN;
    float v[CS]; float mx = -1e30f;
    #pragma unroll
    for (int s = 0; s < CS; s++) { v[s] = dots[(size_t)(b * CS + s) * CN + n]; mx = fmaxf(mx, v[s]); }
    float sum = 0.f;
    #pragma unroll
    for (int s = 0; s < CS; s++) { v[s] = __expf(v[s] - mx); sum += v[s]; }
    float inv = 1.f / sum;
    #pragma unroll
    for (int s = 0; s < CS; s++) dots[(size_t)(b * CS + s) * CN + n] = v[s] * inv + ATTN_EPS;
}

__global__ __launch_bounds__(256) void attn_moments_kernel(float* __restrict__ u,
        float* __restrict__ S_p, float* __restrict__ S_s) {
    __shared__ float sbuf[8];
    int bs = blockIdx.x;
    float* up = u + (size_t)bs * CN;
    float m0 = 0, m1x = 0, m1y = 0, m2x = 0, m2y = 0;
    for (int n = threadIdx.x; n < CN; n += 256) {
        float uu = up[n];
        float ax = ag_x(n), ay = ag_y(n);
        m0 += uu; m1x += uu * ax; m1y += uu * ay; m2x += uu * ax * ax; m2y += uu * ay * ay;
    }
    m0  = block_reduce_sum(m0, sbuf);
    m1x = block_reduce_sum(m1x, sbuf);
    m1y = block_reduce_sum(m1y, sbuf);
    m2x = block_reduce_sum(m2x, sbuf);
    m2y = block_reduce_sum(m2y, sbuf);
    float px = m1x / m0, py = m1y / m0;
    if (threadIdx.x == 0) {
        S_p[2 * bs] = px; S_p[2 * bs + 1] = py;
        S_s[2 * bs]     = sqrtf(fmaxf(m2x / m0 - px * px, 0.f));
        S_s[2 * bs + 1] = sqrtf(fmaxf(m2y / m0 - py * py, 0.f));
    }
    float inv = 1.f / m0;
    for (int n = threadIdx.x; n < CN; n += 256) up[n] = up[n] * inv;   // in-place normalize
}

__global__ __launch_bounds__(256) void gru_mlp_kernel(const float* __restrict__ upd,
        float* __restrict__ slots,
        const float* __restrict__ wih, const float* __restrict__ whh,
        const float* __restrict__ bih, const float* __restrict__ bhh,
        const float* __restrict__ mg, const float* __restrict__ mb,
        const float* __restrict__ w1, const float* __restrict__ b1,
        const float* __restrict__ w2, const float* __restrict__ b2) {
    __shared__ float sU[CD], sH[CD], sM[CD], sH1[4 * CD];
    __shared__ float sbuf[8];
    int row = blockIdx.x, t = threadIdx.x;
    sU[t] = upd[row * CD + t];
    sH[t] = slots[row * CD + t];
    __syncthreads();
    float gi0 = bih[t], gi1 = bih[CD + t], gi2 = bih[2 * CD + t];
    float gh0 = bhh[t], gh1 = bhh[CD + t], gh2 = bhh[2 * CD + t];
    for (int j = 0; j < CD; j++) {
        float uj = sU[j], hj = sH[j];
        gi0 += uj * wih[j * 3 * CD + t];
        gi1 += uj * wih[j * 3 * CD + CD + t];
        gi2 += uj * wih[j * 3 * CD + 2 * CD + t];
        gh0 += hj * whh[j * 3 * CD + t];
        gh1 += hj * whh[j * 3 * CD + CD + t];
        gh2 += hj * whh[j * 3 * CD + 2 * CD + t];
    }
    float r = 1.f / (1.f + expf(-(gi0 + gh0)));
    float z = 1.f / (1.f + expf(-(gi1 + gh1)));
    float nn = tanhf(gi2 + r * gh2);
    float hprev = sH[t];
    float snew = (1.f - z) * nn + z * hprev;
    float mean = block_reduce_sum(snew, sbuf) / CD;
    float dv = snew - mean;
    float var = block_reduce_sum(dv * dv, sbuf) / CD;
    sM[t] = dv * rsqrtf(var + LNEPS) * mg[t] + mb[t];
    __syncthreads();
    #pragma unroll
    for (int o = 0; o < 4; o++) {
        int c = t + o * 256;
        float a = b1[c];
        for (int j = 0; j < CD; j++) a += sM[j] * w1[j * 4 * CD + c];
        sH1[c] = fmaxf(a, 0.f);
    }
    __syncthreads();
    float out = b2[t];
    for (int j = 0; j < 4 * CD; j++) out += sH1[j] * w2[j * CD + t];
    slots[row * CD + t] = snew + out;
}

__global__ __launch_bounds__(256) void final_kernel(const float* __restrict__ slots,
        const float* __restrict__ fw, const float* __restrict__ fb, float* __restrict__ out) {
    __shared__ float sS[CD];
    int row = blockIdx.x, t = threadIdx.x;
    sS[t] = slots[row * CD + t];
    __syncthreads();
    float a = fb[t];
    for (int j = 0; j < CD; j++) a += sS[j] * fw[j * CD + t];
    out[row * CD + t] = a;
}

// ---------------- launcher ----------------
extern "C" void kernel_launch(void* const* d_in, const int* in_sizes, int n_in,
                              void* d_out, int out_size, void* d_ws, size_t ws_size,
                              hipStream_t stream) {
    (void)in_sizes; (void)n_in; (void)out_size;
    const float* inputs       = (const float*)d_in[0];
    const float* slots_init_p = (const float*)d_in[1];
    const float* S_s0         = (const float*)d_in[2];
    const float* S_p0         = (const float*)d_in[3];
    const float* im_ln1_g = (const float*)d_in[4];
    const float* im_ln1_b = (const float*)d_in[5];
    const float* im_w1    = (const float*)d_in[6];
    const float* im_b1    = (const float*)d_in[7];
    const float* im_w2    = (const float*)d_in[8];
    const float* im_b2    = (const float*)d_in[9];
    const float* im_ln2_g = (const float*)d_in[10];
    const float* im_ln2_b = (const float*)d_in[11];
    const float* Wq  = (const float*)d_in[12];
    const float* Wk  = (const float*)d_in[13];
    const float* Wv  = (const float*)d_in[14];
    const float* g_w = (const float*)d_in[15];
    const float* g_b = (const float*)d_in[16];
    const float* f_w1 = (const float*)d_in[17];
    const float* f_b1 = (const float*)d_in[18];
    const float* f_w2 = (const float*)d_in[19];
    const float* f_b2 = (const float*)d_in[20];
    const float* ln_g = (const float*)d_in[21];
    const float* ln_b = (const float*)d_in[22];
    const float* gru_wih = (const float*)d_in[23];
    const float* gru_whh = (const float*)d_in[24];
    const float* gru_bih = (const float*)d_in[25];
    const float* gru_bhh = (const float*)d_in[26];
    const float* mlp_ln_g = (const float*)d_in[27];
    const float* mlp_ln_b = (const float*)d_in[28];
    const float* mlp_w1 = (const float*)d_in[29];
    const float* mlp_b1 = (const float*)d_in[30];
    const float* mlp_w2 = (const float*)d_in[31];
    const float* mlp_b2 = (const float*)d_in[32];
    const float* fin_w = (const float*)d_in[33];
    const float* fin_b = (const float*)d_in[34];

    char* base = (char*)d_ws;
    size_t off = 0;
    auto take = [&](size_t bytes) { void* p = base + off; off += (bytes + 255) & ~(size_t)255; return p; };

    // Region 1: xln [CBN*CDIN] fp32; later xD = R1[0:CBN*CD], xDn = R1[CBN*CD:2*CBN*CD]
    float* R1 = (float*)take((size_t)CBN * CDIN * 4);
    // Region 2: X1 [CBN*CDIN] fp32; later KXW1 = R2[0:CBN*CD], VXW1 = R2[CBN*CD:2*CBN*CD]
    float* R2 = (float*)take((size_t)CBN * CDIN * 4);
    u16* w1th = (u16*)take((size_t)CDIN * CDIN * 2);
    u16* w1tm = (u16*)take((size_t)CDIN * CDIN * 2);
    u16* w1tl = (u16*)take((size_t)CDIN * CDIN * 2);
    u16* w2th = (u16*)take((size_t)CDIN * CD * 2);
    u16* w2tm = (u16*)take((size_t)CDIN * CD * 2);
    u16* w2tl = (u16*)take((size_t)CDIN * CD * 2);
    u16* fw2h = (u16*)take((size_t)CD * CD * 2);
    u16* fw2m = (u16*)take((size_t)CD * CD * 2);
    u16* fw2l = (u16*)take((size_t)CD * CD * 2);
    float* Pk   = (float*)take((size_t)CD * CD * 4);   // Wk @ f_w1 (fp32)
    float* Pv   = (float*)take((size_t)CD * CD * 4);   // Wv @ f_w1
    u16* pkth = (u16*)take((size_t)CD * CD * 2);
    u16* pktm = (u16*)take((size_t)CD * CD * 2);
    u16* pktl = (u16*)take((size_t)CD * CD * 2);
    u16* pvth = (u16*)take((size_t)CD * CD * 2);
    u16* pvtm = (u16*)take((size_t)CD * CD * 2);
    u16* pvtl = (u16*)take((size_t)CD * CD * 2);
    float* G2b  = (float*)take((size_t)2 * CD * 4);    // g_w @ f_w1
    float* gb1b = (float*)take((size_t)CD * 4);        // g_b @ f_w1 + f_b1
    float* relv = (float*)take((size_t)CRT * 2 * 4);   // loop-entry rel snapshot
    float* qb    = (float*)take((size_t)CBS * CD * 4);
    float* S_pb  = (float*)take((size_t)CBS * 2 * 4);
    float* S_sb  = (float*)take((size_t)CBS * 2 * 4);
    float* slots = (float*)take((size_t)CBS * CD * 4);
    float* upd   = (float*)take((size_t)CBS * CD * 4);
    if (ws_size < off) return;   // insufficient workspace (same behavior every call)

    float* xln  = R1;
    float* xD   = R1;                               // reuses xln (dead after X1 GEMM)
    float* xDn  = R1 + (size_t)CBN * CD;
    float* X1   = R2;
    float* KXW1 = R2;                               // reuses X1 (dead after xD GEMM)
    float* VXW1 = R2 + (size_t)CBN * CD;

    float* out0 = (float*)d_out;            // [CBS,CD]
    float* attnb = out0 + CBS * CD;         // [CBS,CN] — doubles as dots buffer

    dim3 blk(256);
    const int gM_bn = (CBN + 127) / 128;    // 86
    const int gM_rt = (CRT + 127) / 128;    // 599
    const float* NUL = nullptr;

    // ---- weight prep ----
    transpose_split3_kernel<<<dim3(CDIN/32, CDIN/32), blk, 0, stream>>>(im_w1, w1th, w1tm, w1tl, CDIN, CDIN);
    transpose_split3_kernel<<<dim3(CD/32,   CDIN/32), blk, 0, stream>>>(im_w2, w2th, w2tm, w2tl, CDIN, CD);
    transpose_split3_kernel<<<dim3(CD/32,   CD/32),   blk, 0, stream>>>(f_w2, fw2h, fw2m, fw2l, CD, CD);
    wprod_kernel<<<CD, blk, 0, stream>>>(Wk, f_w1, Pk);          // Pk = Wk @ f_w1
    wprod_kernel<<<CD, blk, 0, stream>>>(Wv, f_w1, Pv);
    transpose_split3_kernel<<<dim3(CD/32, CD/32), blk, 0, stream>>>(Pk, pkth, pktm, pktl, CD, CD);
    transpose_split3_kernel<<<dim3(CD/32, CD/32), blk, 0, stream>>>(Pv, pvth, pvtm, pvtl, CD, CD);
    g2_kernel<<<1, blk, 0, stream>>>(g_w, g_b, f_w1, f_b1, G2b, gb1b);

    // ---- initial mlp:  xln -> X1 -> xD -> ln2 -> xDn;  KXW1 = xDn@Pk, VXW1 = xDn@Pv ----
    ln_kernel<<<CBN, blk, 0, stream>>>(inputs, xln, im_ln1_g, im_ln1_b, CDIN);
    hgemm<0,0><<<dim3(gM_bn, CDIN/128), blk, 0, stream>>>(xln, w1th, w1tm, w1tl, CBN, CDIN, CDIN,
        im_b1, 1, X1, NUL, NUL, NUL, NUL, NUL, nullptr, NUL, nullptr);
    hgemm<0,0><<<dim3(gM_bn, CD/128), blk, 0, stream>>>(X1, w2th, w2tm, w2tl, CBN, CD, CDIN,
        im_b2, 0, xD, NUL, NUL, NUL, NUL, NUL, nullptr, NUL, nullptr);
    ln_kernel<<<CBN, blk, 0, stream>>>(xD, xDn, im_ln2_g, im_ln2_b, CD);
    hgemm<0,0><<<dim3(gM_bn, CD/128), blk, 0, stream>>>(xDn, pkth, pktm, pktl, CBN, CD, CD,
        nullptr, 0, KXW1, NUL, NUL, NUL, NUL, NUL, nullptr, NUL, nullptr);
    hgemm<0,0><<<dim3(gM_bn, CD/128), blk, 0, stream>>>(xDn, pvth, pvtm, pvtl, CBN, CD, CD,
        nullptr, 0, VXW1, NUL, NUL, NUL, NUL, NUL, nullptr, NUL, nullptr);
    init_kernel<<<CBS, blk, 0, stream>>>(slots_init_p, S_s0, S_p0, slots, S_sb, S_pb);

    for (int t = 0; t <= CITERS; t++) {
        slots_q_kernel<<<CBS, blk, 0, stream>>>(slots, ln_g, ln_b, Wq, qb);
        // rel snapshot from loop-entry S_p/S_s — used by BOTH k and v paths this iteration
        rel_kernel<<<(CRT + 255) / 256, blk, 0, stream>>>(S_pb, S_sb, relv);
        hipMemsetAsync(attnb, 0, (size_t)CRT * sizeof(float), stream);
        // fused: dots = (relu(KXW1 + rel@G2 + gb1) @ f_w2 + f_b2) . q * scale
        hgemm<2,2><<<dim3(gM_rt, CD/128), blk, 0, stream>>>(NUL, fw2h, fw2m, fw2l, CRT, CD, CD,
            f_b2, 0, nullptr, KXW1, relv, G2b, gb1b, qb, attnb, NUL, nullptr);
        softmax_kernel<<<(CBN + 255) / 256, blk, 0, stream>>>(attnb);
        attn_moments_kernel<<<CBS, blk, 0, stream>>>(attnb, S_pb, S_sb);
        if (t < CITERS) {
            hipMemsetAsync(upd, 0, (size_t)CBS * CD * sizeof(float), stream);
            // fused: upd = attn-weighted rows of (relu(VXW1 + rel@G2 + gb1) @ f_w2 + f_b2)
            hgemm<2,3><<<dim3(gM_rt, CD/128), blk, 0, stream>>>(NUL, fw2h, fw2m, fw2l, CRT, CD, CD,
                f_b2, 0, nullptr, VXW1, relv, G2b, gb1b, NUL, nullptr, attnb, upd);
            gru_mlp_kernel<<<CBS, blk, 0, stream>>>(upd, slots, gru_wih, gru_whh, gru_bih, gru_bhh,
                mlp_ln_g, mlp_ln_b, mlp_w1, mlp_b1, mlp_w2, mlp_b2);
        }
    }
    final_kernel<<<CBS, blk, 0, stream>>>(slots, fin_w, fin_b, out0);
}

// Round 7
// 1279.319 us; speedup vs baseline: 2.1816x; 1.1224x over previous
//
#include <hip/hip_runtime.h>

// ---------------- problem constants ----------------
constexpr int CB   = 8;      // batch
constexpr int CN   = 1369;   // tokens (37*37)
constexpr int CDIN = 768;
constexpr int CS   = 7;      // slots
constexpr int CD   = 256;
constexpr int CITERS = 3;
constexpr int CRES = 37;
constexpr float CSIGMA = 5.0f;
constexpr int CBS = CB * CS;        // 56
constexpr int CRT = CBS * CN;       // 76664 rows for f_mlp
constexpr int CBN = CB * CN;        // 10952 rows for initial mlp
constexpr float LNEPS = 1e-5f;
constexpr float ATTN_EPS = 1e-8f;

typedef unsigned short u16;
typedef short bs8 __attribute__((ext_vector_type(8)));   // 8 bf16 (bit pattern in shorts)
typedef float f4 __attribute__((ext_vector_type(4)));

// ---------------- helpers ----------------
__device__ __forceinline__ float ag_x(int n) { return -1.f + (float)(n % CRES) * (2.f / 36.f); }
__device__ __forceinline__ float ag_y(int n) { return -1.f + (float)(n / CRES) * (2.f / 36.f); }

__device__ __forceinline__ u16 bf_rne(float f) {
    unsigned u = __float_as_uint(f);
    return (u16)((u + 0x7FFFu + ((u >> 16) & 1u)) >> 16);
}
__device__ __forceinline__ float bf_to_f(u16 h) { return __uint_as_float(((unsigned)h) << 16); }

// v = h + m with each plane bf16 (RNE); residual <= 2^-18 |v|
__device__ __forceinline__ void split2b(float v, u16& h, u16& m) {
    h = bf_rne(v);
    m = bf_rne(v - bf_to_f(h));
}

// 256-thread block sum
__device__ __forceinline__ float block_reduce_sum(float v, float* sbuf) {
    #pragma unroll
    for (int off = 32; off > 0; off >>= 1) v += __shfl_down(v, off, 64);
    if ((threadIdx.x & 63) == 0) sbuf[threadIdx.x >> 6] = v;
    __syncthreads();
    if (threadIdx.x == 0) sbuf[0] = sbuf[0] + sbuf[1] + sbuf[2] + sbuf[3];
    __syncthreads();
    float r = sbuf[0];
    __syncthreads();
    return r;
}

// ---------------- layernorm (fp32 out) ----------------
__global__ __launch_bounds__(256) void ln_kernel(const float* __restrict__ in,
        float* __restrict__ out, const float* __restrict__ g,
        const float* __restrict__ b, int d) {
    __shared__ float sbuf[8];
    int row = blockIdx.x;
    const float* x = in + (size_t)row * d;
    float* y = out + (size_t)row * d;
    float s = 0.f;
    for (int i = threadIdx.x; i < d; i += 256) s += x[i];
    float mean = block_reduce_sum(s, sbuf) / d;
    float v = 0.f;
    for (int i = threadIdx.x; i < d; i += 256) { float t = x[i] - mean; v += t * t; }
    float var = block_reduce_sum(v, sbuf) / d;
    float rstd = rsqrtf(var + LNEPS);
    for (int i = threadIdx.x; i < d; i += 256) y[i] = (x[i] - mean) * rstd * g[i] + b[i];
}

// ---------------- transpose fp32 W[K][N] -> 2 bf16 planes Wt[N][K] ----------------
__global__ __launch_bounds__(256) void transpose_split2_kernel(const float* __restrict__ W,
        u16* __restrict__ Th, u16* __restrict__ Tm, int K, int N) {
    __shared__ float tile[32][33];
    int nb = blockIdx.x * 32, kb = blockIdx.y * 32;
    int tx = threadIdx.x & 31, ty = threadIdx.x >> 5;   // ty 0..7
    #pragma unroll
    for (int i = 0; i < 32; i += 8)
        tile[ty + i][tx] = W[(size_t)(kb + ty + i) * N + nb + tx];
    __syncthreads();
    #pragma unroll
    for (int i = 0; i < 32; i += 8) {
        float v = tile[tx][ty + i];
        u16 h, m; split2b(v, h, m);
        size_t idx = (size_t)(nb + ty + i) * K + kb + tx;
        Th[idx] = h; Tm[idx] = m;
    }
}

// ---------------- small fp32 weight-product: P[k][n] = sum_j A[k][j]*B[j][n], all [256][256] ----------------
__global__ __launch_bounds__(256) void wprod_kernel(const float* __restrict__ A,
        const float* __restrict__ B, float* __restrict__ P) {
    __shared__ float arow[CD];
    int k = blockIdx.x, n = threadIdx.x;
    arow[n] = A[k * CD + n];
    __syncthreads();
    float acc = 0.f;
    for (int j = 0; j < CD; j++) acc += arow[j] * B[j * CD + n];
    P[k * CD + n] = acc;
}

// G2[g][n] = sum_j g_w[g][j]*f_w1[j][n];  gb1[n] = sum_j g_b[j]*f_w1[j][n] + f_b1[n]
__global__ __launch_bounds__(256) void g2_kernel(const float* __restrict__ g_w,
        const float* __restrict__ g_b, const float* __restrict__ f_w1,
        const float* __restrict__ f_b1, float* __restrict__ G2, float* __restrict__ gb1) {
    int n = threadIdx.x;
    float a0 = 0.f, a1 = 0.f, ab = 0.f;
    for (int j = 0; j < CD; j++) {
        float w = f_w1[j * CD + n];
        a0 += g_w[j] * w;
        a1 += g_w[CD + j] * w;
        ab += g_b[j] * w;
    }
    G2[n] = a0; G2[CD + n] = a1; gb1[n] = ab + f_b1[n];
}

// ---------------- rel materialization (loop-entry S_p/S_s snapshot, shared by k and v paths) ----------------
__global__ __launch_bounds__(256) void rel_kernel(const float* __restrict__ S_p,
        const float* __restrict__ S_s, float* __restrict__ relv) {
    int r = blockIdx.x * 256 + threadIdx.x;
    if (r >= CRT) return;
    int bs = r / CN;
    int n = r - bs * CN;
    relv[2 * r]     = (ag_x(n) - S_p[2 * bs])     / (S_s[2 * bs]     * CSIGMA);
    relv[2 * r + 1] = (ag_y(n) - S_p[2 * bs + 1]) / (S_s[2 * bs + 1] * CSIGMA);
}

// ---------------- bf16x3 (split-2 planes) TN GEMM ----------------
// C[m][n] = act( sum_k A[m][k]*Bt[n][k] + bias[n] ); 3 MFMAs/tile: hh, mh, hm.
// AMODE 0: A from fp32 array [M][K].
// AMODE 2: A built = relu( SRC[(b,n)][k] + r0*G2[0][k] + r1*G2[1][k] + gb1[k] )  (fused f_mlp layer-1)
// EPI 0: store fp32. EPI 2: dots[m] += scale * C[m][:].q[bs(m)][:]. EPI 3: upd[bs(m)][n] += attn[m]*C[m][n]
template<int AMODE, int EPI>
__global__ __launch_bounds__(256)
void hgemm(const float* __restrict__ A,
           const u16* __restrict__ Bh, const u16* __restrict__ Bm,
           int M, int N, int K, const float* __restrict__ bias, int relu,
           float* __restrict__ Cf,
           const float* __restrict__ SRC, const float* __restrict__ relv,
           const float* __restrict__ gw, const float* __restrict__ gb,
           const float* __restrict__ qv, float* __restrict__ dots,
           const float* __restrict__ attn, float* __restrict__ upd) {
    constexpr int PK = 40;                       // padded K-stride (32 + 8)
    __shared__ short smem[4 * 128 * PK];         // 40 KB: Ah|Am|Bh|Bm
    short* Ash = smem;
    short* Asm_ = smem + 128 * PK;
    short* Bsh = smem + 2 * 128 * PK;
    short* Bsm = smem + 3 * 128 * PK;
    const int tid = threadIdx.x;
    const int m0 = blockIdx.x * 128, n0 = blockIdx.y * 128;
    const int w = tid >> 6, lane = tid & 63;
    const int wm = w & 1, wn = w >> 1;
    const int l15 = lane & 15, l4 = lane >> 4;
    const int sr = tid >> 2;                    // staging row 0..63
    const int sc = (tid & 3) * 8;               // staging col 0/8/16/24

    float r0[2], r1[2]; const float* asrc[2];
    #pragma unroll
    for (int it = 0; it < 2; it++) {
        int grow = m0 + sr + it * 64;
        int gcl = grow < M ? grow : M - 1;
        if constexpr (AMODE == 2) {
            int bs = gcl / CN;
            int n = gcl - bs * CN;
            int b = bs / CS;
            asrc[it] = SRC + (size_t)(b * CN + n) * CD + sc;
            r0[it] = relv[2 * gcl];
            r1[it] = relv[2 * gcl + 1];
        } else {
            asrc[it] = A + (size_t)gcl * K + sc;
        }
    }

    f4 acc[4][4];
    #pragma unroll
    for (int i = 0; i < 4; i++)
        #pragma unroll
        for (int j = 0; j < 4; j++) acc[i][j] = (f4){0.f, 0.f, 0.f, 0.f};

    for (int k0 = 0; k0 < K; k0 += 32) {
        #pragma unroll
        for (int it = 0; it < 2; it++) {
            int r = sr + it * 64;
            float v8[8];
            const float* p = asrc[it] + k0;
            *(float4*)&v8[0] = *(const float4*)(p);
            *(float4*)&v8[4] = *(const float4*)(p + 4);
            if constexpr (AMODE == 2) {
                float g0v[8], g1v[8], gbv[8];
                *(float4*)&g0v[0] = *(const float4*)(gw + k0 + sc);
                *(float4*)&g0v[4] = *(const float4*)(gw + k0 + sc + 4);
                *(float4*)&g1v[0] = *(const float4*)(gw + CD + k0 + sc);
                *(float4*)&g1v[4] = *(const float4*)(gw + CD + k0 + sc + 4);
                *(float4*)&gbv[0] = *(const float4*)(gb + k0 + sc);
                *(float4*)&gbv[4] = *(const float4*)(gb + k0 + sc + 4);
                #pragma unroll
                for (int j = 0; j < 8; j++)
                    v8[j] = fmaxf(v8[j] + r0[it] * g0v[j] + r1[it] * g1v[j] + gbv[j], 0.f);
            }
            bs8 hv, mv;
            #pragma unroll
            for (int j = 0; j < 8; j++) {
                u16 h, m; split2b(v8[j], h, m);
                hv[j] = (short)h; mv[j] = (short)m;
            }
            *(bs8*)(Ash  + r * PK + sc) = hv;
            *(bs8*)(Asm_ + r * PK + sc) = mv;
            int nr = n0 + r;
            size_t bofs = (size_t)nr * K + k0 + sc;
            *(bs8*)(Bsh + r * PK + sc) = *(const bs8*)(Bh + bofs);
            *(bs8*)(Bsm + r * PK + sc) = *(const bs8*)(Bm + bofs);
        }
        __syncthreads();
        bs8 ah[4], am[4], bh[4], bm[4];
        #pragma unroll
        for (int f = 0; f < 4; f++) {
            int ra = (wm * 64 + f * 16 + l15) * PK + l4 * 8;
            ah[f] = *(const bs8*)(Ash  + ra);
            am[f] = *(const bs8*)(Asm_ + ra);
            int rb = (wn * 64 + f * 16 + l15) * PK + l4 * 8;
            bh[f] = *(const bs8*)(Bsh + rb);
            bm[f] = *(const bs8*)(Bsm + rb);
        }
        #pragma unroll
        for (int mf = 0; mf < 4; mf++)
            #pragma unroll
            for (int nf = 0; nf < 4; nf++) {
                acc[mf][nf] = __builtin_amdgcn_mfma_f32_16x16x32_bf16(am[mf], bh[nf], acc[mf][nf], 0, 0, 0);
                acc[mf][nf] = __builtin_amdgcn_mfma_f32_16x16x32_bf16(ah[mf], bm[nf], acc[mf][nf], 0, 0, 0);
                acc[mf][nf] = __builtin_amdgcn_mfma_f32_16x16x32_bf16(ah[mf], bh[nf], acc[mf][nf], 0, 0, 0);
            }
        __syncthreads();
    }

    if constexpr (EPI == 0) {
        #pragma unroll
        for (int mf = 0; mf < 4; mf++)
            #pragma unroll
            for (int i = 0; i < 4; i++) {
                int grow = m0 + wm * 64 + mf * 16 + l4 * 4 + i;
                if (grow < M) {
                    #pragma unroll
                    for (int nf = 0; nf < 4; nf++) {
                        int col = n0 + wn * 64 + nf * 16 + l15;
                        float v = acc[mf][nf][i] + (bias ? bias[col] : 0.f);
                        if (relu) v = fmaxf(v, 0.f);
                        Cf[(size_t)grow * N + col] = v;
                    }
                }
            }
    } else if constexpr (EPI == 2) {
        float* red = (float*)smem;   // [128][32] = 16 KB
        #pragma unroll
        for (int mf = 0; mf < 4; mf++)
            #pragma unroll
            for (int i = 0; i < 4; i++) {
                int row_l = wm * 64 + mf * 16 + l4 * 4 + i;
                int grow = m0 + row_l;
                float p = 0.f;
                if (grow < M) {
                    int bs = grow / CN;
                    #pragma unroll
                    for (int nf = 0; nf < 4; nf++) {
                        int col = n0 + wn * 64 + nf * 16 + l15;
                        p += (acc[mf][nf][i] + bias[col]) * qv[bs * CD + col];
                    }
                }
                red[row_l * 32 + wn * 16 + l15] = p;
            }
        __syncthreads();
        if (tid < 128) {
            int grow = m0 + tid;
            if (grow < M) {
                float s = 0.f;
                #pragma unroll
                for (int c = 0; c < 32; c++) s += red[tid * 32 + c];
                atomicAdd(&dots[grow], s * 0.0625f);   // * D^-0.5
            }
        }
    } else {  // EPI == 3
        float* red = (float*)smem;   // [128][8]
        int bs0 = m0 / CN;
        int bnd = (bs0 + 1) * CN;
        for (int g = 0; g < 2; g++) {
            __syncthreads();
            #pragma unroll
            for (int nf = 0; nf < 4; nf++) {
                float s = 0.f;
                #pragma unroll
                for (int mf = 0; mf < 4; mf++)
                    #pragma unroll
                    for (int i = 0; i < 4; i++) {
                        int grow = m0 + wm * 64 + mf * 16 + l4 * 4 + i;
                        int gg = grow >= bnd ? 1 : 0;
                        if (grow < M && gg == g) {
                            int col = n0 + wn * 64 + nf * 16 + l15;
                            s += (acc[mf][nf][i] + bias[col]) * attn[grow];
                        }
                    }
                int col_l = wn * 64 + nf * 16 + l15;
                red[col_l * 8 + wm * 4 + l4] = s;
            }
            __syncthreads();
            if (tid < 128) {
                int bsg = bs0 + g;
                if (bsg < CBS) {
                    float s = 0.f;
                    #pragma unroll
                    for (int c = 0; c < 8; c++) s += red[tid * 8 + c];
                    atomicAdd(&upd[bsg * CD + n0 + tid], s);
                }
            }
        }
    }
}

// ---------------- small kernels ----------------
__global__ __launch_bounds__(256) void init_kernel(const float* __restrict__ slots_init_p,
        const float* __restrict__ S_s0, const float* __restrict__ S_p0,
        float* __restrict__ slots, float* __restrict__ S_s, float* __restrict__ S_p) {
    int bs = blockIdx.x, t = threadIdx.x;
    int s = bs % CS;
    slots[bs * CD + t] = slots_init_p[s * CD + t];
    if (t < 2) { S_s[bs * 2 + t] = S_s0[s * 2 + t]; S_p[bs * 2 + t] = S_p0[s * 2 + t]; }
}

__global__ __launch_bounds__(256) void slots_q_kernel(const float* __restrict__ slots,
        const float* __restrict__ ln_g, const float* __restrict__ ln_b,
        const float* __restrict__ Wq, float* __restrict__ q) {
    __shared__ float sn[CD];
    __shared__ float sbuf[8];
    int row = blockIdx.x, t = threadIdx.x;
    float x = slots[row * CD + t];
    float mean = block_reduce_sum(x, sbuf) / CD;
    float d0 = x - mean;
    float var = block_reduce_sum(d0 * d0, sbuf) / CD;
    sn[t] = d0 * rsqrtf(var + LNEPS) * ln_g[t] + ln_b[t];
    __syncthreads();
    float acc = 0.f;
    for (int j = 0; j < CD; j++) acc += sn[j] * Wq[j * CD + t];
    q[row * CD + t] = acc;
}

__global__ __launch_bounds__(256) void softmax_kernel(float* __restrict__ dots) {
    int idx = blockIdx.x * 256 + threadIdx.x;
    if (idx >= CBN) return;
    int b = idx / CN, n = idx - b * CN;
    float v[CS]; float mx = -1e30f;
    #pragma unroll
    for (int s = 0; s < CS; s++) { v[s] = dots[(size_t)(b * CS + s) * CN + n]; mx = fmaxf(mx, v[s]); }
    float sum = 0.f;
    #pragma unroll
    for (int s = 0; s < CS; s++) { v[s] = __expf(v[s] - mx); sum += v[s]; }
    float inv = 1.f / sum;
    #pragma unroll
    for (int s = 0; s < CS; s++) dots[(size_t)(b * CS + s) * CN + n] = v[s] * inv + ATTN_EPS;
}

__global__ __launch_bounds__(256) void attn_moments_kernel(float* __restrict__ u,
        float* __restrict__ S_p, float* __restrict__ S_s) {
    __shared__ float sbuf[8];
    int bs = blockIdx.x;
    float* up = u + (size_t)bs * CN;
    float m0 = 0, m1x = 0, m1y = 0, m2x = 0, m2y = 0;
    for (int n = threadIdx.x; n < CN; n += 256) {
        float uu = up[n];
        float ax = ag_x(n), ay = ag_y(n);
        m0 += uu; m1x += uu * ax; m1y += uu * ay; m2x += uu * ax * ax; m2y += uu * ay * ay;
    }
    m0  = block_reduce_sum(m0, sbuf);
    m1x = block_reduce_sum(m1x, sbuf);
    m1y = block_reduce_sum(m1y, sbuf);
    m2x = block_reduce_sum(m2x, sbuf);
    m2y = block_reduce_sum(m2y, sbuf);
    float px = m1x / m0, py = m1y / m0;
    if (threadIdx.x == 0) {
        S_p[2 * bs] = px; S_p[2 * bs + 1] = py;
        S_s[2 * bs]     = sqrtf(fmaxf(m2x / m0 - px * px, 0.f));
        S_s[2 * bs + 1] = sqrtf(fmaxf(m2y / m0 - py * py, 0.f));
    }
    float inv = 1.f / m0;
    for (int n = threadIdx.x; n < CN; n += 256) up[n] = up[n] * inv;   // in-place normalize
}

__global__ __launch_bounds__(256) void gru_mlp_kernel(const float* __restrict__ upd,
        float* __restrict__ slots,
        const float* __restrict__ wih, const float* __restrict__ whh,
        const float* __restrict__ bih, const float* __restrict__ bhh,
        const float* __restrict__ mg, const float* __restrict__ mb,
        const float* __restrict__ w1, const float* __restrict__ b1,
        const float* __restrict__ w2, const float* __restrict__ b2) {
    __shared__ float sU[CD], sH[CD], sM[CD], sH1[4 * CD];
    __shared__ float sbuf[8];
    int row = blockIdx.x, t = threadIdx.x;
    sU[t] = upd[row * CD + t];
    sH[t] = slots[row * CD + t];
    __syncthreads();
    float gi0 = bih[t], gi1 = bih[CD + t], gi2 = bih[2 * CD + t];
    float gh0 = bhh[t], gh1 = bhh[CD + t], gh2 = bhh[2 * CD + t];
    for (int j = 0; j < CD; j++) {
        float uj = sU[j], hj = sH[j];
        gi0 += uj * wih[j * 3 * CD + t];
        gi1 += uj * wih[j * 3 * CD + CD + t];
        gi2 += uj * wih[j * 3 * CD + 2 * CD + t];
        gh0 += hj * whh[j * 3 * CD + t];
        gh1 += hj * whh[j * 3 * CD + CD + t];
        gh2 += hj * whh[j * 3 * CD + 2 * CD + t];
    }
    float r = 1.f / (1.f + expf(-(gi0 + gh0)));
    float z = 1.f / (1.f + expf(-(gi1 + gh1)));
    float nn = tanhf(gi2 + r * gh2);
    float hprev = sH[t];
    float snew = (1.f - z) * nn + z * hprev;
    float mean = block_reduce_sum(snew, sbuf) / CD;
    float dv = snew - mean;
    float var = block_reduce_sum(dv * dv, sbuf) / CD;
    sM[t] = dv * rsqrtf(var + LNEPS) * mg[t] + mb[t];
    __syncthreads();
    #pragma unroll
    for (int o = 0; o < 4; o++) {
        int c = t + o * 256;
        float a = b1[c];
        for (int j = 0; j < CD; j++) a += sM[j] * w1[j * 4 * CD + c];
        sH1[c] = fmaxf(a, 0.f);
    }
    __syncthreads();
    float out = b2[t];
    for (int j = 0; j < 4 * CD; j++) out += sH1[j] * w2[j * CD + t];
    slots[row * CD + t] = snew + out;
}

__global__ __launch_bounds__(256) void final_kernel(const float* __restrict__ slots,
        const float* __restrict__ fw, const float* __restrict__ fb, float* __restrict__ out) {
    __shared__ float sS[CD];
    int row = blockIdx.x, t = threadIdx.x;
    sS[t] = slots[row * CD + t];
    __syncthreads();
    float a = fb[t];
    for (int j = 0; j < CD; j++) a += sS[j] * fw[j * CD + t];
    out[row * CD + t] = a;
}

// ---------------- launcher ----------------
extern "C" void kernel_launch(void* const* d_in, const int* in_sizes, int n_in,
                              void* d_out, int out_size, void* d_ws, size_t ws_size,
                              hipStream_t stream) {
    (void)in_sizes; (void)n_in; (void)out_size;
    const float* inputs       = (const float*)d_in[0];
    const float* slots_init_p = (const float*)d_in[1];
    const float* S_s0         = (const float*)d_in[2];
    const float* S_p0         = (const float*)d_in[3];
    const float* im_ln1_g = (const float*)d_in[4];
    const float* im_ln1_b = (const float*)d_in[5];
    const float* im_w1    = (const float*)d_in[6];
    const float* im_b1    = (const float*)d_in[7];
    const float* im_w2    = (const float*)d_in[8];
    const float* im_b2    = (const float*)d_in[9];
    const float* im_ln2_g = (const float*)d_in[10];
    const float* im_ln2_b = (const float*)d_in[11];
    const float* Wq  = (const float*)d_in[12];
    const float* Wk  = (const float*)d_in[13];
    const float* Wv  = (const float*)d_in[14];
    const float* g_w = (const float*)d_in[15];
    const float* g_b = (const float*)d_in[16];
    const float* f_w1 = (const float*)d_in[17];
    const float* f_b1 = (const float*)d_in[18];
    const float* f_w2 = (const float*)d_in[19];
    const float* f_b2 = (const float*)d_in[20];
    const float* ln_g = (const float*)d_in[21];
    const float* ln_b = (const float*)d_in[22];
    const float* gru_wih = (const float*)d_in[23];
    const float* gru_whh = (const float*)d_in[24];
    const float* gru_bih = (const float*)d_in[25];
    const float* gru_bhh = (const float*)d_in[26];
    const float* mlp_ln_g = (const float*)d_in[27];
    const float* mlp_ln_b = (const float*)d_in[28];
    const float* mlp_w1 = (const float*)d_in[29];
    const float* mlp_b1 = (const float*)d_in[30];
    const float* mlp_w2 = (const float*)d_in[31];
    const float* mlp_b2 = (const float*)d_in[32];
    const float* fin_w = (const float*)d_in[33];
    const float* fin_b = (const float*)d_in[34];

    char* base = (char*)d_ws;
    size_t off = 0;
    auto take = [&](size_t bytes) { void* p = base + off; off += (bytes + 255) & ~(size_t)255; return p; };

    // Region 1: xln [CBN*CDIN] fp32; later xD = R1[0:CBN*CD], xDn = R1[CBN*CD:2*CBN*CD]
    float* R1 = (float*)take((size_t)CBN * CDIN * 4);
    // Region 2: X1 [CBN*CDIN] fp32; later KXW1 = R2[0:CBN*CD], VXW1 = R2[CBN*CD:2*CBN*CD]
    float* R2 = (float*)take((size_t)CBN * CDIN * 4);
    u16* w1th = (u16*)take((size_t)CDIN * CDIN * 2);
    u16* w1tm = (u16*)take((size_t)CDIN * CDIN * 2);
    u16* w2th = (u16*)take((size_t)CDIN * CD * 2);
    u16* w2tm = (u16*)take((size_t)CDIN * CD * 2);
    u16* fw2h = (u16*)take((size_t)CD * CD * 2);
    u16* fw2m = (u16*)take((size_t)CD * CD * 2);
    float* Pk   = (float*)take((size_t)CD * CD * 4);   // Wk @ f_w1 (fp32)
    float* Pv   = (float*)take((size_t)CD * CD * 4);   // Wv @ f_w1
    u16* pkth = (u16*)take((size_t)CD * CD * 2);
    u16* pktm = (u16*)take((size_t)CD * CD * 2);
    u16* pvth = (u16*)take((size_t)CD * CD * 2);
    u16* pvtm = (u16*)take((size_t)CD * CD * 2);
    float* G2b  = (float*)take((size_t)2 * CD * 4);    // g_w @ f_w1
    float* gb1b = (float*)take((size_t)CD * 4);        // g_b @ f_w1 + f_b1
    float* relv = (float*)take((size_t)CRT * 2 * 4);   // loop-entry rel snapshot
    float* qb    = (float*)take((size_t)CBS * CD * 4);
    float* S_pb  = (float*)take((size_t)CBS * 2 * 4);
    float* S_sb  = (float*)take((size_t)CBS * 2 * 4);
    float* slots = (float*)take((size_t)CBS * CD * 4);
    float* upd   = (float*)take((size_t)CBS * CD * 4);
    if (ws_size < off) return;   // insufficient workspace (same behavior every call)

    float* xln  = R1;
    float* xD   = R1;                               // reuses xln (dead after X1 GEMM)
    float* xDn  = R1 + (size_t)CBN * CD;
    float* X1   = R2;
    float* KXW1 = R2;                               // reuses X1 (dead after xD GEMM)
    float* VXW1 = R2 + (size_t)CBN * CD;

    float* out0 = (float*)d_out;            // [CBS,CD]
    float* attnb = out0 + CBS * CD;         // [CBS,CN] — doubles as dots buffer

    dim3 blk(256);
    const int gM_bn = (CBN + 127) / 128;    // 86
    const int gM_rt = (CRT + 127) / 128;    // 599
    const float* NUL = nullptr;

    // ---- weight prep ----
    transpose_split2_kernel<<<dim3(CDIN/32, CDIN/32), blk, 0, stream>>>(im_w1, w1th, w1tm, CDIN, CDIN);
    transpose_split2_kernel<<<dim3(CD/32,   CDIN/32), blk, 0, stream>>>(im_w2, w2th, w2tm, CDIN, CD);
    transpose_split2_kernel<<<dim3(CD/32,   CD/32),   blk, 0, stream>>>(f_w2, fw2h, fw2m, CD, CD);
    wprod_kernel<<<CD, blk, 0, stream>>>(Wk, f_w1, Pk);          // Pk = Wk @ f_w1
    wprod_kernel<<<CD, blk, 0, stream>>>(Wv, f_w1, Pv);
    transpose_split2_kernel<<<dim3(CD/32, CD/32), blk, 0, stream>>>(Pk, pkth, pktm, CD, CD);
    transpose_split2_kernel<<<dim3(CD/32, CD/32), blk, 0, stream>>>(Pv, pvth, pvtm, CD, CD);
    g2_kernel<<<1, blk, 0, stream>>>(g_w, g_b, f_w1, f_b1, G2b, gb1b);

    // ---- initial mlp:  xln -> X1 -> xD -> ln2 -> xDn;  KXW1 = xDn@Pk, VXW1 = xDn@Pv ----
    ln_kernel<<<CBN, blk, 0, stream>>>(inputs, xln, im_ln1_g, im_ln1_b, CDIN);
    hgemm<0,0><<<dim3(gM_bn, CDIN/128), blk, 0, stream>>>(xln, w1th, w1tm, CBN, CDIN, CDIN,
        im_b1, 1, X1, NUL, NUL, NUL, NUL, NUL, nullptr, NUL, nullptr);
    hgemm<0,0><<<dim3(gM_bn, CD/128), blk, 0, stream>>>(X1, w2th, w2tm, CBN, CD, CDIN,
        im_b2, 0, xD, NUL, NUL, NUL, NUL, NUL, nullptr, NUL, nullptr);
    ln_kernel<<<CBN, blk, 0, stream>>>(xD, xDn, im_ln2_g, im_ln2_b, CD);
    hgemm<0,0><<<dim3(gM_bn, CD/128), blk, 0, stream>>>(xDn, pkth, pktm, CBN, CD, CD,
        nullptr, 0, KXW1, NUL, NUL, NUL, NUL, NUL, nullptr, NUL, nullptr);
    hgemm<0,0><<<dim3(gM_bn, CD/128), blk, 0, stream>>>(xDn, pvth, pvtm, CBN, CD, CD,
        nullptr, 0, VXW1, NUL, NUL, NUL, NUL, NUL, nullptr, NUL, nullptr);
    init_kernel<<<CBS, blk, 0, stream>>>(slots_init_p, S_s0, S_p0, slots, S_sb, S_pb);

    for (int t = 0; t <= CITERS; t++) {
        slots_q_kernel<<<CBS, blk, 0, stream>>>(slots, ln_g, ln_b, Wq, qb);
        // rel snapshot from loop-entry S_p/S_s — used by BOTH k and v paths this iteration
        rel_kernel<<<(CRT + 255) / 256, blk, 0, stream>>>(S_pb, S_sb, relv);
        hipMemsetAsync(attnb, 0, (size_t)CRT * sizeof(float), stream);
        // fused: dots = (relu(KXW1 + rel@G2 + gb1) @ f_w2 + f_b2) . q * scale
        hgemm<2,2><<<dim3(gM_rt, CD/128), blk, 0, stream>>>(NUL, fw2h, fw2m, CRT, CD, CD,
            f_b2, 0, nullptr, KXW1, relv, G2b, gb1b, qb, attnb, NUL, nullptr);
        softmax_kernel<<<(CBN + 255) / 256, blk, 0, stream>>>(attnb);
        attn_moments_kernel<<<CBS, blk, 0, stream>>>(attnb, S_pb, S_sb);
        if (t < CITERS) {
            hipMemsetAsync(upd, 0, (size_t)CBS * CD * sizeof(float), stream);
            // fused: upd = attn-weighted rows of (relu(VXW1 + rel@G2 + gb1) @ f_w2 + f_b2)
            hgemm<2,3><<<dim3(gM_rt, CD/128), blk, 0, stream>>>(NUL, fw2h, fw2m, CRT, CD, CD,
                f_b2, 0, nullptr, VXW1, relv, G2b, gb1b, NUL, nullptr, attnb, upd);
            gru_mlp_kernel<<<CBS, blk, 0, stream>>>(upd, slots, gru_wih, gru_whh, gru_bih, gru_bhh,
                mlp_ln_g, mlp_ln_b, mlp_w1, mlp_b1, mlp_w2, mlp_b2);
        }
    }
    final_kernel<<<CBS, blk, 0, stream>>>(slots, fin_w, fin_b, out0);
}

// Round 8
// 941.370 us; speedup vs baseline: 2.9647x; 1.3590x over previous
//
#include <hip/hip_runtime.h>

// ---------------- problem constants ----------------
constexpr int CB   = 8;      // batch
constexpr int CN   = 1369;   // tokens (37*37)
constexpr int CDIN = 768;
constexpr int CS   = 7;      // slots
constexpr int CD   = 256;
constexpr int CITERS = 3;
constexpr int CRES = 37;
constexpr float CSIGMA = 5.0f;
constexpr int CBS = CB * CS;        // 56
constexpr int CBN = CB * CN;        // 10952 rows for initial mlp
constexpr float LNEPS = 1e-5f;
constexpr float ATTN_EPS = 1e-8f;

typedef unsigned short u16;
typedef short bs8 __attribute__((ext_vector_type(8)));   // 8 bf16 (bit pattern in shorts)
typedef float f4 __attribute__((ext_vector_type(4)));

// ---------------- helpers ----------------
__device__ __forceinline__ float ag_x(int n) { return -1.f + (float)(n % CRES) * (2.f / 36.f); }
__device__ __forceinline__ float ag_y(int n) { return -1.f + (float)(n / CRES) * (2.f / 36.f); }

__device__ __forceinline__ u16 bf_rne(float f) {
    unsigned u = __float_as_uint(f);
    return (u16)((u + 0x7FFFu + ((u >> 16) & 1u)) >> 16);
}
__device__ __forceinline__ float bf_to_f(u16 h) { return __uint_as_float(((unsigned)h) << 16); }

__device__ __forceinline__ void split2b(float v, u16& h, u16& m) {
    h = bf_rne(v);
    m = bf_rne(v - bf_to_f(h));
}

// 256-thread block sum
__device__ __forceinline__ float block_reduce_sum(float v, float* sbuf) {
    #pragma unroll
    for (int off = 32; off > 0; off >>= 1) v += __shfl_down(v, off, 64);
    if ((threadIdx.x & 63) == 0) sbuf[threadIdx.x >> 6] = v;
    __syncthreads();
    if (threadIdx.x == 0) sbuf[0] = sbuf[0] + sbuf[1] + sbuf[2] + sbuf[3];
    __syncthreads();
    float r = sbuf[0];
    __syncthreads();
    return r;
}

// 1024-thread block sum
__device__ __forceinline__ float block_reduce_1024(float v, float* sbuf) {
    #pragma unroll
    for (int off = 32; off > 0; off >>= 1) v += __shfl_down(v, off, 64);
    if ((threadIdx.x & 63) == 0) sbuf[threadIdx.x >> 6] = v;
    __syncthreads();
    if (threadIdx.x == 0) {
        float s = 0.f;
        #pragma unroll
        for (int i = 0; i < 16; i++) s += sbuf[i];
        sbuf[0] = s;
    }
    __syncthreads();
    float r = sbuf[0];
    __syncthreads();
    return r;
}

// ---------------- layernorm (fp32 out) ----------------
__global__ __launch_bounds__(256) void ln_kernel(const float* __restrict__ in,
        float* __restrict__ out, const float* __restrict__ g,
        const float* __restrict__ b, int d) {
    __shared__ float sbuf[8];
    int row = blockIdx.x;
    const float* x = in + (size_t)row * d;
    float* y = out + (size_t)row * d;
    float s = 0.f;
    for (int i = threadIdx.x; i < d; i += 256) s += x[i];
    float mean = block_reduce_sum(s, sbuf) / d;
    float v = 0.f;
    for (int i = threadIdx.x; i < d; i += 256) { float t = x[i] - mean; v += t * t; }
    float var = block_reduce_sum(v, sbuf) / d;
    float rstd = rsqrtf(var + LNEPS);
    for (int i = threadIdx.x; i < d; i += 256) y[i] = (x[i] - mean) * rstd * g[i] + b[i];
}

// ---------------- transpose fp32 W[K][N] -> 2 bf16 planes Wt[N][K] ----------------
__global__ __launch_bounds__(256) void transpose_split2_kernel(const float* __restrict__ W,
        u16* __restrict__ Th, u16* __restrict__ Tm, int K, int N) {
    __shared__ float tile[32][33];
    int nb = blockIdx.x * 32, kb = blockIdx.y * 32;
    int tx = threadIdx.x & 31, ty = threadIdx.x >> 5;   // ty 0..7
    #pragma unroll
    for (int i = 0; i < 32; i += 8)
        tile[ty + i][tx] = W[(size_t)(kb + ty + i) * N + nb + tx];
    __syncthreads();
    #pragma unroll
    for (int i = 0; i < 32; i += 8) {
        float v = tile[tx][ty + i];
        u16 h, m; split2b(v, h, m);
        size_t idx = (size_t)(nb + ty + i) * K + kb + tx;
        Th[idx] = h; Tm[idx] = m;
    }
}

// ---------------- small fp32 weight-product: P[k][n] = sum_j A[k][j]*B[j][n], all [256][256] ----------------
__global__ __launch_bounds__(256) void wprod_kernel(const float* __restrict__ A,
        const float* __restrict__ B, float* __restrict__ P) {
    __shared__ float arow[CD];
    int k = blockIdx.x, n = threadIdx.x;
    arow[n] = A[k * CD + n];
    __syncthreads();
    float acc = 0.f;
    for (int j = 0; j < CD; j++) acc += arow[j] * B[j * CD + n];
    P[k * CD + n] = acc;
}

// G2[g][n] = sum_j g_w[g][j]*f_w1[j][n];  gb1[n] = sum_j g_b[j]*f_w1[j][n] + f_b1[n]
__global__ __launch_bounds__(256) void g2_kernel(const float* __restrict__ g_w,
        const float* __restrict__ g_b, const float* __restrict__ f_w1,
        const float* __restrict__ f_b1, float* __restrict__ G2, float* __restrict__ gb1) {
    int n = threadIdx.x;
    float a0 = 0.f, a1 = 0.f, ab = 0.f;
    for (int j = 0; j < CD; j++) {
        float w = f_w1[j * CD + n];
        a0 += g_w[j] * w;
        a1 += g_w[CD + j] * w;
        ab += g_b[j] * w;
    }
    G2[n] = a0; G2[CD + n] = a1; gb1[n] = ab + f_b1[n];
}

// ---------------- bf16x3 (split-2 planes) TN GEMM — init phase only ----------------
__global__ __launch_bounds__(256)
void hgemm(const float* __restrict__ A,
           const u16* __restrict__ Bh, const u16* __restrict__ Bm,
           int M, int N, int K, const float* __restrict__ bias, int relu,
           float* __restrict__ Cf) {
    constexpr int PK = 40;                       // padded K-stride (32 + 8)
    __shared__ short smem[4 * 128 * PK];         // 40 KB: Ah|Am|Bh|Bm
    short* Ash = smem;
    short* Asm_ = smem + 128 * PK;
    short* Bsh = smem + 2 * 128 * PK;
    short* Bsm = smem + 3 * 128 * PK;
    const int tid = threadIdx.x;
    const int m0 = blockIdx.x * 128, n0 = blockIdx.y * 128;
    const int w = tid >> 6, lane = tid & 63;
    const int wm = w & 1, wn = w >> 1;
    const int l15 = lane & 15, l4 = lane >> 4;
    const int sr = tid >> 2;
    const int sc = (tid & 3) * 8;

    const float* asrc[2];
    #pragma unroll
    for (int it = 0; it < 2; it++) {
        int grow = m0 + sr + it * 64;
        int gcl = grow < M ? grow : M - 1;
        asrc[it] = A + (size_t)gcl * K + sc;
    }

    f4 acc[4][4];
    #pragma unroll
    for (int i = 0; i < 4; i++)
        #pragma unroll
        for (int j = 0; j < 4; j++) acc[i][j] = (f4){0.f, 0.f, 0.f, 0.f};

    for (int k0 = 0; k0 < K; k0 += 32) {
        #pragma unroll
        for (int it = 0; it < 2; it++) {
            int r = sr + it * 64;
            float v8[8];
            const float* p = asrc[it] + k0;
            *(float4*)&v8[0] = *(const float4*)(p);
            *(float4*)&v8[4] = *(const float4*)(p + 4);
            bs8 hv, mv;
            #pragma unroll
            for (int j = 0; j < 8; j++) {
                u16 h, m; split2b(v8[j], h, m);
                hv[j] = (short)h; mv[j] = (short)m;
            }
            *(bs8*)(Ash  + r * PK + sc) = hv;
            *(bs8*)(Asm_ + r * PK + sc) = mv;
            int nr = n0 + r;
            size_t bofs = (size_t)nr * K + k0 + sc;
            *(bs8*)(Bsh + r * PK + sc) = *(const bs8*)(Bh + bofs);
            *(bs8*)(Bsm + r * PK + sc) = *(const bs8*)(Bm + bofs);
        }
        __syncthreads();
        bs8 ah[4], am[4], bh[4], bm[4];
        #pragma unroll
        for (int f = 0; f < 4; f++) {
            int ra = (wm * 64 + f * 16 + l15) * PK + l4 * 8;
            ah[f] = *(const bs8*)(Ash  + ra);
            am[f] = *(const bs8*)(Asm_ + ra);
            int rb = (wn * 64 + f * 16 + l15) * PK + l4 * 8;
            bh[f] = *(const bs8*)(Bsh + rb);
            bm[f] = *(const bs8*)(Bsm + rb);
        }
        #pragma unroll
        for (int mf = 0; mf < 4; mf++)
            #pragma unroll
            for (int nf = 0; nf < 4; nf++) {
                acc[mf][nf] = __builtin_amdgcn_mfma_f32_16x16x32_bf16(am[mf], bh[nf], acc[mf][nf], 0, 0, 0);
                acc[mf][nf] = __builtin_amdgcn_mfma_f32_16x16x32_bf16(ah[mf], bm[nf], acc[mf][nf], 0, 0, 0);
                acc[mf][nf] = __builtin_amdgcn_mfma_f32_16x16x32_bf16(ah[mf], bh[nf], acc[mf][nf], 0, 0, 0);
            }
        __syncthreads();
    }

    #pragma unroll
    for (int mf = 0; mf < 4; mf++)
        #pragma unroll
        for (int i = 0; i < 4; i++) {
            int grow = m0 + wm * 64 + mf * 16 + l4 * 4 + i;
            if (grow < M) {
                #pragma unroll
                for (int nf = 0; nf < 4; nf++) {
                    int col = n0 + wn * 64 + nf * 16 + l15;
                    float v = acc[mf][nf][i] + (bias ? bias[col] : 0.f);
                    if (relu) v = fmaxf(v, 0.f);
                    Cf[(size_t)grow * N + col] = v;
                }
            }
        }
}

// ---------------- small kernels ----------------
__global__ __launch_bounds__(256) void init_kernel(const float* __restrict__ slots_init_p,
        const float* __restrict__ S_s0, const float* __restrict__ S_p0,
        float* __restrict__ slots, float* __restrict__ S_s, float* __restrict__ S_p) {
    int bs = blockIdx.x, t = threadIdx.x;
    int s = bs % CS;
    slots[bs * CD + t] = slots_init_p[s * CD + t];
    if (t < 2) { S_s[bs * 2 + t] = S_s0[s * 2 + t]; S_p[bs * 2 + t] = S_p0[s * 2 + t]; }
}

__global__ __launch_bounds__(256) void slots_q_kernel(const float* __restrict__ slots,
        const float* __restrict__ ln_g, const float* __restrict__ ln_b,
        const float* __restrict__ Wq, float* __restrict__ q) {
    __shared__ float sn[CD];
    __shared__ float sbuf[8];
    int row = blockIdx.x, t = threadIdx.x;
    float x = slots[row * CD + t];
    float mean = block_reduce_sum(x, sbuf) / CD;
    float d0 = x - mean;
    float var = block_reduce_sum(d0 * d0, sbuf) / CD;
    sn[t] = d0 * rsqrtf(var + LNEPS) * ln_g[t] + ln_b[t];
    __syncthreads();
    float acc = 0.f;
    for (int j = 0; j < CD; j++) acc += sn[j] * Wq[j * CD + t];
    q[row * CD + t] = acc;
}

// qw[bs][k] = sum_c f_w2[k][c]*q[bs][c]   (via transposed planes, coalesced)
// qb0[bs] = q[bs] . f_b2
__global__ __launch_bounds__(256) void qw_kernel(const float* __restrict__ qv,
        const u16* __restrict__ fw2h, const u16* __restrict__ fw2m,
        const float* __restrict__ f_b2, float* __restrict__ qw, float* __restrict__ qb0) {
    __shared__ float sq[CD];
    __shared__ float sbuf[8];
    int bs = blockIdx.x, k = threadIdx.x;
    sq[k] = qv[bs * CD + k];
    __syncthreads();
    float a = 0.f;
    for (int c = 0; c < CD; c++)
        a += sq[c] * (bf_to_f(fw2h[(size_t)c * CD + k]) + bf_to_f(fw2m[(size_t)c * CD + k]));
    qw[bs * CD + k] = a;
    float qb = block_reduce_sum(sq[k] * f_b2[k], sbuf);
    if (k == 0) qb0[bs] = qb;
}

// dots[(b,s),n] = scale*( qw[bs] . relu(KXW1[b,n] + r0*G2[0] + r1*G2[1] + gb1) + qb0[bs] )
__global__ __launch_bounds__(256) void dots_kernel(const float* __restrict__ KXW1,
        const float* __restrict__ S_p, const float* __restrict__ S_s,
        const float* __restrict__ G2, const float* __restrict__ gb1,
        const float* __restrict__ qw, const float* __restrict__ qb0,
        float* __restrict__ dots) {
    int b = blockIdx.x;
    int w = threadIdx.x >> 6, l = threadIdx.x & 63;
    int k4 = l * 4;
    float4 g0 = *(const float4*)(G2 + k4);
    float4 g1 = *(const float4*)(G2 + CD + k4);
    float4 gb = *(const float4*)(gb1 + k4);
    float4 qwv[CS]; float px[CS], py[CS], ix[CS], iy[CS], q0[CS];
    #pragma unroll
    for (int s = 0; s < CS; s++) {
        int bs = b * CS + s;
        qwv[s] = *(const float4*)(qw + bs * CD + k4);
        px[s] = S_p[2 * bs]; py[s] = S_p[2 * bs + 1];
        ix[s] = 1.f / (S_s[2 * bs] * CSIGMA); iy[s] = 1.f / (S_s[2 * bs + 1] * CSIGMA);
        q0[s] = qb0[bs];
    }
    for (int i = 0; i < 8; i++) {
        int n = blockIdx.y * 32 + w * 8 + i;
        if (n >= CN) break;
        float4 kx = *(const float4*)(KXW1 + (size_t)(b * CN + n) * CD + k4);
        float ax = ag_x(n), ay = ag_y(n);
        #pragma unroll
        for (int s = 0; s < CS; s++) {
            float r0 = (ax - px[s]) * ix[s];
            float r1 = (ay - py[s]) * iy[s];
            float v0 = fmaxf(kx.x + r0 * g0.x + r1 * g1.x + gb.x, 0.f);
            float v1 = fmaxf(kx.y + r0 * g0.y + r1 * g1.y + gb.y, 0.f);
            float v2 = fmaxf(kx.z + r0 * g0.z + r1 * g1.z + gb.z, 0.f);
            float v3 = fmaxf(kx.w + r0 * g0.w + r1 * g1.w + gb.w, 0.f);
            float d = v0 * qwv[s].x + v1 * qwv[s].y + v2 * qwv[s].z + v3 * qwv[s].w;
            #pragma unroll
            for (int off = 32; off > 0; off >>= 1) d += __shfl_down(d, off, 64);
            if (l == 0) dots[(size_t)(b * CS + s) * CN + n] = 0.0625f * (d + q0[s]);
        }
    }
}

// Wacc[bs][k] += sum_n attn[bs,n] * relu(VXW1[b,n,k] + r0*G2[0][k] + r1*G2[1][k] + gb1[k])
__global__ __launch_bounds__(256) void vsum_kernel(const float* __restrict__ VXW1,
        const float* __restrict__ S_p, const float* __restrict__ S_s,
        const float* __restrict__ G2, const float* __restrict__ gb1,
        const float* __restrict__ attn, float* __restrict__ Wacc) {
    __shared__ float sred[4 * CD];
    int b = blockIdx.x;
    int w = threadIdx.x >> 6, l = threadIdx.x & 63;
    int k4 = l * 4;
    float4 g0 = *(const float4*)(G2 + k4);
    float4 g1 = *(const float4*)(G2 + CD + k4);
    float4 gb = *(const float4*)(gb1 + k4);
    float px[CS], py[CS], ix[CS], iy[CS];
    #pragma unroll
    for (int s = 0; s < CS; s++) {
        int bs = b * CS + s;
        px[s] = S_p[2 * bs]; py[s] = S_p[2 * bs + 1];
        ix[s] = 1.f / (S_s[2 * bs] * CSIGMA); iy[s] = 1.f / (S_s[2 * bs + 1] * CSIGMA);
    }
    float4 acc[CS];
    #pragma unroll
    for (int s = 0; s < CS; s++) acc[s] = make_float4(0.f, 0.f, 0.f, 0.f);
    for (int i = 0; i < 8; i++) {
        int n = blockIdx.y * 32 + w * 8 + i;
        if (n >= CN) break;
        float4 vx = *(const float4*)(VXW1 + (size_t)(b * CN + n) * CD + k4);
        float ax = ag_x(n), ay = ag_y(n);
        #pragma unroll
        for (int s = 0; s < CS; s++) {
            float r0 = (ax - px[s]) * ix[s];
            float r1 = (ay - py[s]) * iy[s];
            float a = attn[(size_t)(b * CS + s) * CN + n];
            acc[s].x += a * fmaxf(vx.x + r0 * g0.x + r1 * g1.x + gb.x, 0.f);
            acc[s].y += a * fmaxf(vx.y + r0 * g0.y + r1 * g1.y + gb.y, 0.f);
            acc[s].z += a * fmaxf(vx.z + r0 * g0.z + r1 * g1.z + gb.z, 0.f);
            acc[s].w += a * fmaxf(vx.w + r0 * g0.w + r1 * g1.w + gb.w, 0.f);
        }
    }
    for (int s = 0; s < CS; s++) {
        ((float4*)sred)[w * 64 + l] = acc[s];
        __syncthreads();
        if (threadIdx.x < CD) {
            float v = sred[threadIdx.x] + sred[CD + threadIdx.x]
                    + sred[2 * CD + threadIdx.x] + sred[3 * CD + threadIdx.x];
            atomicAdd(&Wacc[(size_t)(b * CS + s) * CD + threadIdx.x], v);
        }
        __syncthreads();
    }
}

// upd[bs][c] = Wacc[bs] @ f_w2[:,c] + f_b2[c]
__global__ __launch_bounds__(256) void updgemm_kernel(const float* __restrict__ Wacc,
        const float* __restrict__ f_w2, const float* __restrict__ f_b2,
        float* __restrict__ upd) {
    __shared__ float sw[CD];
    int bs = blockIdx.x, c = threadIdx.x;
    sw[c] = Wacc[bs * CD + c];
    __syncthreads();
    float a = f_b2[c];
    for (int k = 0; k < CD; k++) a += sw[k] * f_w2[(size_t)k * CD + c];
    upd[bs * CD + c] = a;
}

__global__ __launch_bounds__(256) void softmax_kernel(float* __restrict__ dots) {
    int idx = blockIdx.x * 256 + threadIdx.x;
    if (idx >= CBN) return;
    int b = idx / CN, n = idx - b * CN;
    float v[CS]; float mx = -1e30f;
    #pragma unroll
    for (int s = 0; s < CS; s++) { v[s] = dots[(size_t)(b * CS + s) * CN + n]; mx = fmaxf(mx, v[s]); }
    float sum = 0.f;
    #pragma unroll
    for (int s = 0; s < CS; s++) { v[s] = __expf(v[s] - mx); sum += v[s]; }
    float inv = 1.f / sum;
    #pragma unroll
    for (int s = 0; s < CS; s++) dots[(size_t)(b * CS + s) * CN + n] = v[s] * inv + ATTN_EPS;
}

__global__ __launch_bounds__(256) void attn_moments_kernel(float* __restrict__ u,
        float* __restrict__ S_p, float* __restrict__ S_s) {
    __shared__ float sbuf[8];
    int bs = blockIdx.x;
    float* up = u + (size_t)bs * CN;
    float m0 = 0, m1x = 0, m1y = 0, m2x = 0, m2y = 0;
    for (int n = threadIdx.x; n < CN; n += 256) {
        float uu = up[n];
        float ax = ag_x(n), ay = ag_y(n);
        m0 += uu; m1x += uu * ax; m1y += uu * ay; m2x += uu * ax * ax; m2y += uu * ay * ay;
    }
    m0  = block_reduce_sum(m0, sbuf);
    m1x = block_reduce_sum(m1x, sbuf);
    m1y = block_reduce_sum(m1y, sbuf);
    m2x = block_reduce_sum(m2x, sbuf);
    m2y = block_reduce_sum(m2y, sbuf);
    float px = m1x / m0, py = m1y / m0;
    if (threadIdx.x == 0) {
        S_p[2 * bs] = px; S_p[2 * bs + 1] = py;
        S_s[2 * bs]     = sqrtf(fmaxf(m2x / m0 - px * px, 0.f));
        S_s[2 * bs + 1] = sqrtf(fmaxf(m2y / m0 - py * py, 0.f));
    }
    float inv = 1.f / m0;
    for (int n = threadIdx.x; n < CN; n += 256) up[n] = up[n] * inv;   // in-place normalize
}

// ---------------- GRU + residual MLP, 1024 threads, K-split 4-way ----------------
__global__ __launch_bounds__(1024) void gru_mlp2_kernel(const float* __restrict__ upd,
        float* __restrict__ slots,
        const float* __restrict__ wih, const float* __restrict__ whh,
        const float* __restrict__ bih, const float* __restrict__ bhh,
        const float* __restrict__ mg, const float* __restrict__ mb,
        const float* __restrict__ w1, const float* __restrict__ b1,
        const float* __restrict__ w2, const float* __restrict__ b2) {
    __shared__ float sU[CD], sH[CD], sP[6 * 1024], sM[CD], sSnew[CD], sH1[4 * CD];
    __shared__ float sbuf[16];
    int row = blockIdx.x, tid = threadIdx.x;
    int t = tid & 255, kq = tid >> 8;
    if (tid < CD) { sU[tid] = upd[row * CD + tid]; sH[tid] = slots[row * CD + tid]; }
    __syncthreads();
    float a0 = 0, a1 = 0, a2 = 0, h0 = 0, h1 = 0, h2 = 0;
    int j0 = kq * 64;
    for (int j = j0; j < j0 + 64; j++) {
        float uj = sU[j], hj = sH[j];
        const float* wi = wih + (size_t)j * (3 * CD) + t;
        a0 += uj * wi[0]; a1 += uj * wi[CD]; a2 += uj * wi[2 * CD];
        const float* wh = whh + (size_t)j * (3 * CD) + t;
        h0 += hj * wh[0]; h1 += hj * wh[CD]; h2 += hj * wh[2 * CD];
    }
    sP[(0 * 4 + kq) * 256 + t] = a0; sP[(1 * 4 + kq) * 256 + t] = a1; sP[(2 * 4 + kq) * 256 + t] = a2;
    sP[(3 * 4 + kq) * 256 + t] = h0; sP[(4 * 4 + kq) * 256 + t] = h1; sP[(5 * 4 + kq) * 256 + t] = h2;
    __syncthreads();
    float snew = 0.f;
    if (kq == 0) {
        float gi0 = bih[t], gi1 = bih[CD + t], gi2 = bih[2 * CD + t];
        float gh0 = bhh[t], gh1 = bhh[CD + t], gh2 = bhh[2 * CD + t];
        #pragma unroll
        for (int q = 0; q < 4; q++) {
            gi0 += sP[(0 * 4 + q) * 256 + t]; gi1 += sP[(1 * 4 + q) * 256 + t]; gi2 += sP[(2 * 4 + q) * 256 + t];
            gh0 += sP[(3 * 4 + q) * 256 + t]; gh1 += sP[(4 * 4 + q) * 256 + t]; gh2 += sP[(5 * 4 + q) * 256 + t];
        }
        float r = 1.f / (1.f + expf(-(gi0 + gh0)));
        float z = 1.f / (1.f + expf(-(gi1 + gh1)));
        float nn = tanhf(gi2 + r * gh2);
        snew = (1.f - z) * nn + z * sH[t];
        sSnew[t] = snew;
    }
    __syncthreads();
    float mean = block_reduce_1024(kq == 0 ? snew : 0.f, sbuf) / CD;
    float dv = (kq == 0) ? (snew - mean) : 0.f;
    float var = block_reduce_1024(dv * dv, sbuf) / CD;
    float rstd = rsqrtf(var + LNEPS);
    if (kq == 0) sM[t] = (snew - mean) * rstd * mg[t] + mb[t];
    __syncthreads();
    // MLP layer 1: 1024 outputs, one per thread
    float a = b1[tid];
    for (int j = 0; j < CD; j++) a += sM[j] * w1[(size_t)j * (4 * CD) + tid];
    sH1[tid] = fmaxf(a, 0.f);
    __syncthreads();
    // MLP layer 2: 256 outputs, K-split 4-way
    float o = 0.f;
    int jj0 = kq * 256;
    for (int j = jj0; j < jj0 + 256; j++) o += sH1[j] * w2[(size_t)j * CD + t];
    sP[kq * 256 + t] = o;
    __syncthreads();
    if (kq == 0)
        slots[row * CD + t] = sSnew[t] + b2[t] + sP[t] + sP[256 + t] + sP[512 + t] + sP[768 + t];
}

__global__ __launch_bounds__(256) void final_kernel(const float* __restrict__ slots,
        const float* __restrict__ fw, const float* __restrict__ fb, float* __restrict__ out) {
    __shared__ float sS[CD];
    int row = blockIdx.x, t = threadIdx.x;
    sS[t] = slots[row * CD + t];
    __syncthreads();
    float a = fb[t];
    for (int j = 0; j < CD; j++) a += sS[j] * fw[j * CD + t];
    out[row * CD + t] = a;
}

// ---------------- launcher ----------------
extern "C" void kernel_launch(void* const* d_in, const int* in_sizes, int n_in,
                              void* d_out, int out_size, void* d_ws, size_t ws_size,
                              hipStream_t stream) {
    (void)in_sizes; (void)n_in; (void)out_size;
    const float* inputs       = (const float*)d_in[0];
    const float* slots_init_p = (const float*)d_in[1];
    const float* S_s0         = (const float*)d_in[2];
    const float* S_p0         = (const float*)d_in[3];
    const float* im_ln1_g = (const float*)d_in[4];
    const float* im_ln1_b = (const float*)d_in[5];
    const float* im_w1    = (const float*)d_in[6];
    const float* im_b1    = (const float*)d_in[7];
    const float* im_w2    = (const float*)d_in[8];
    const float* im_b2    = (const float*)d_in[9];
    const float* im_ln2_g = (const float*)d_in[10];
    const float* im_ln2_b = (const float*)d_in[11];
    const float* Wq  = (const float*)d_in[12];
    const float* Wk  = (const float*)d_in[13];
    const float* Wv  = (const float*)d_in[14];
    const float* g_w = (const float*)d_in[15];
    const float* g_b = (const float*)d_in[16];
    const float* f_w1 = (const float*)d_in[17];
    const float* f_b1 = (const float*)d_in[18];
    const float* f_w2 = (const float*)d_in[19];
    const float* f_b2 = (const float*)d_in[20];
    const float* ln_g = (const float*)d_in[21];
    const float* ln_b = (const float*)d_in[22];
    const float* gru_wih = (const float*)d_in[23];
    const float* gru_whh = (const float*)d_in[24];
    const float* gru_bih = (const float*)d_in[25];
    const float* gru_bhh = (const float*)d_in[26];
    const float* mlp_ln_g = (const float*)d_in[27];
    const float* mlp_ln_b = (const float*)d_in[28];
    const float* mlp_w1 = (const float*)d_in[29];
    const float* mlp_b1 = (const float*)d_in[30];
    const float* mlp_w2 = (const float*)d_in[31];
    const float* mlp_b2 = (const float*)d_in[32];
    const float* fin_w = (const float*)d_in[33];
    const float* fin_b = (const float*)d_in[34];

    char* base = (char*)d_ws;
    size_t off = 0;
    auto take = [&](size_t bytes) { void* p = base + off; off += (bytes + 255) & ~(size_t)255; return p; };

    float* R1 = (float*)take((size_t)CBN * CDIN * 4);  // xln; later xD | xDn
    float* R2 = (float*)take((size_t)CBN * CDIN * 4);  // X1; later KXW1 | VXW1
    u16* w1th = (u16*)take((size_t)CDIN * CDIN * 2);
    u16* w1tm = (u16*)take((size_t)CDIN * CDIN * 2);
    u16* w2th = (u16*)take((size_t)CDIN * CD * 2);
    u16* w2tm = (u16*)take((size_t)CDIN * CD * 2);
    u16* fw2h = (u16*)take((size_t)CD * CD * 2);
    u16* fw2m = (u16*)take((size_t)CD * CD * 2);
    float* Pk   = (float*)take((size_t)CD * CD * 4);
    float* Pv   = (float*)take((size_t)CD * CD * 4);
    u16* pkth = (u16*)take((size_t)CD * CD * 2);
    u16* pktm = (u16*)take((size_t)CD * CD * 2);
    u16* pvth = (u16*)take((size_t)CD * CD * 2);
    u16* pvtm = (u16*)take((size_t)CD * CD * 2);
    float* G2b  = (float*)take((size_t)2 * CD * 4);
    float* gb1b = (float*)take((size_t)CD * 4);
    float* qb    = (float*)take((size_t)CBS * CD * 4);
    float* qwb   = (float*)take((size_t)CBS * CD * 4);
    float* qb0b  = (float*)take((size_t)CBS * 4);
    float* Wacc  = (float*)take((size_t)CBS * CD * 4);
    float* S_pA  = (float*)take((size_t)CBS * 2 * 4);
    float* S_sA  = (float*)take((size_t)CBS * 2 * 4);
    float* S_pB  = (float*)take((size_t)CBS * 2 * 4);
    float* S_sB  = (float*)take((size_t)CBS * 2 * 4);
    float* slots = (float*)take((size_t)CBS * CD * 4);
    float* upd   = (float*)take((size_t)CBS * CD * 4);
    if (ws_size < off) return;

    float* xln  = R1;
    float* xD   = R1;
    float* xDn  = R1 + (size_t)CBN * CD;
    float* X1   = R2;
    float* KXW1 = R2;
    float* VXW1 = R2 + (size_t)CBN * CD;

    float* out0 = (float*)d_out;            // [CBS,CD]
    float* attnb = out0 + CBS * CD;         // [CBS,CN] — dots/attn buffer

    dim3 blk(256);
    const int gM_bn = (CBN + 127) / 128;    // 86
    dim3 gridBN(CB, (CN + 31) / 32);        // 8 x 43

    // ---- weight prep ----
    transpose_split2_kernel<<<dim3(CDIN/32, CDIN/32), blk, 0, stream>>>(im_w1, w1th, w1tm, CDIN, CDIN);
    transpose_split2_kernel<<<dim3(CD/32,   CDIN/32), blk, 0, stream>>>(im_w2, w2th, w2tm, CDIN, CD);
    transpose_split2_kernel<<<dim3(CD/32,   CD/32),   blk, 0, stream>>>(f_w2, fw2h, fw2m, CD, CD);
    wprod_kernel<<<CD, blk, 0, stream>>>(Wk, f_w1, Pk);
    wprod_kernel<<<CD, blk, 0, stream>>>(Wv, f_w1, Pv);
    transpose_split2_kernel<<<dim3(CD/32, CD/32), blk, 0, stream>>>(Pk, pkth, pktm, CD, CD);
    transpose_split2_kernel<<<dim3(CD/32, CD/32), blk, 0, stream>>>(Pv, pvth, pvtm, CD, CD);
    g2_kernel<<<1, blk, 0, stream>>>(g_w, g_b, f_w1, f_b1, G2b, gb1b);

    // ---- initial mlp ----
    ln_kernel<<<CBN, blk, 0, stream>>>(inputs, xln, im_ln1_g, im_ln1_b, CDIN);
    hgemm<<<dim3(gM_bn, CDIN/128), blk, 0, stream>>>(xln, w1th, w1tm, CBN, CDIN, CDIN, im_b1, 1, X1);
    hgemm<<<dim3(gM_bn, CD/128), blk, 0, stream>>>(X1, w2th, w2tm, CBN, CD, CDIN, im_b2, 0, xD);
    ln_kernel<<<CBN, blk, 0, stream>>>(xD, xDn, im_ln2_g, im_ln2_b, CD);
    hgemm<<<dim3(gM_bn, CD/128), blk, 0, stream>>>(xDn, pkth, pktm, CBN, CD, CD, nullptr, 0, KXW1);
    hgemm<<<dim3(gM_bn, CD/128), blk, 0, stream>>>(xDn, pvth, pvtm, CBN, CD, CD, nullptr, 0, VXW1);
    init_kernel<<<CBS, blk, 0, stream>>>(slots_init_p, S_s0, S_p0, slots, S_sA, S_pA);

    for (int t = 0; t <= CITERS; t++) {
        float* Sp_cur = (t & 1) ? S_pB : S_pA;
        float* Ss_cur = (t & 1) ? S_sB : S_sA;
        float* Sp_nxt = (t & 1) ? S_pA : S_pB;
        float* Ss_nxt = (t & 1) ? S_sA : S_sB;
        slots_q_kernel<<<CBS, blk, 0, stream>>>(slots, ln_g, ln_b, Wq, qb);
        qw_kernel<<<CBS, blk, 0, stream>>>(qb, fw2h, fw2m, f_b2, qwb, qb0b);
        dots_kernel<<<gridBN, blk, 0, stream>>>(KXW1, Sp_cur, Ss_cur, G2b, gb1b, qwb, qb0b, attnb);
        softmax_kernel<<<(CBN + 255) / 256, blk, 0, stream>>>(attnb);
        attn_moments_kernel<<<CBS, blk, 0, stream>>>(attnb, Sp_nxt, Ss_nxt);
        if (t < CITERS) {
            hipMemsetAsync(Wacc, 0, (size_t)CBS * CD * sizeof(float), stream);
            vsum_kernel<<<gridBN, blk, 0, stream>>>(VXW1, Sp_cur, Ss_cur, G2b, gb1b, attnb, Wacc);
            updgemm_kernel<<<CBS, blk, 0, stream>>>(Wacc, f_w2, f_b2, upd);
            gru_mlp2_kernel<<<CBS, dim3(1024), 0, stream>>>(upd, slots, gru_wih, gru_whh,
                gru_bih, gru_bhh, mlp_ln_g, mlp_ln_b, mlp_w1, mlp_b1, mlp_w2, mlp_b2);
        }
    }
    final_kernel<<<CBS, blk, 0, stream>>>(slots, fin_w, fin_b, out0);
}